// Round 3
// baseline (472.930 us; speedup 1.0000x reference)
//
#include <hip/hip_runtime.h>
#include <math.h>

typedef unsigned short u16;
typedef unsigned int u32;
typedef __bf16 bf16x8 __attribute__((ext_vector_type(8)));
typedef unsigned short us8 __attribute__((ext_vector_type(8)));
typedef unsigned short us4 __attribute__((ext_vector_type(4)));
typedef float f32x4 __attribute__((ext_vector_type(4)));

#define DEV __device__ __forceinline__

DEV float fast_exp2(float x) { return __builtin_amdgcn_exp2f(x); }

DEV u16 f2bf(float f) {
  u32 u = __builtin_bit_cast(u32, f);
  u += 0x7fff + ((u >> 16) & 1);
  return (u16)(u >> 16);
}

DEV bf16x8 ld_bf8(const u16* p) { return __builtin_bit_cast(bf16x8, *(const us8*)p); }

DEV void gload_lds16(const u16* g, u16* l) {
  __builtin_amdgcn_global_load_lds((const __attribute__((address_space(1))) void*)g,
                                   (__attribute__((address_space(3))) void*)l, 16, 0, 0);
}

DEV f32x4 mfma16(bf16x8 a, bf16x8 b, f32x4 c) {
  return __builtin_amdgcn_mfma_f32_16x16x32_bf16(a, b, c, 0, 0, 0);
}

// ---------------- prep kernels ----------------

__global__ void conv_bf16_kernel(const float* __restrict__ in, u16* __restrict__ out, int n4) {
  const int stride = gridDim.x * blockDim.x;
  for (int i = blockIdx.x * blockDim.x + threadIdx.x; i < n4; i += stride) {
    float4 v = ((const float4*)in)[i];
    us4 h; h[0] = f2bf(v.x); h[1] = f2bf(v.y); h[2] = f2bf(v.z); h[3] = f2bf(v.w);
    ((us4*)out)[i] = h;
  }
}

// in: K x N f32 (row-major) -> out: N x K bf16 (B^T), times scale.
// P=0 plain; P=1 permute OUT row c' = ((c&15)<<6)|(c>>4) (head-major q/k, N==1024);
// P=2 gather IN row  src  = ((r&63)<<4)|(r>>6)           (wo: K index head-major, K==1024)
template <int P>
__global__ __launch_bounds__(256) void transpose_bf16_kernel(
    const float* __restrict__ in, u16* __restrict__ out, int K, int N, float scale) {
  __shared__ float tile[32][33];
  const int nbk = K >> 5;
  const int bk = blockIdx.x % nbk, bn = blockIdx.x / nbk;
  const int r0 = bk << 5, c0 = bn << 5;
  const int t = threadIdx.x;
  {
    const int r = t >> 3, c4 = (t & 7) << 2;
    int sr = r0 + r;
    if constexpr (P == 2) sr = ((sr & 63) << 4) | (sr >> 6);
    const float4 v = *(const float4*)(in + (size_t)sr * N + c0 + c4);
    tile[r][c4] = v.x; tile[r][c4 + 1] = v.y; tile[r][c4 + 2] = v.z; tile[r][c4 + 3] = v.w;
  }
  __syncthreads();
  {
    const int oc = t >> 3, r4 = (t & 7) << 2;
    int orow = c0 + oc;
    if constexpr (P == 1) orow = ((orow & 15) << 6) | (orow >> 4);
    us4 h;
#pragma unroll
    for (int j = 0; j < 4; j++) h[j] = f2bf(tile[r4 + j][oc] * scale);
    *(us4*)(out + (size_t)orow * K + r0 + r4) = h;
  }
}

// k half of qk [b][l][1024 + n*64 + d] -> kth [b][n][d][l]
__global__ __launch_bounds__(256) void khead_transpose(
    const u16* __restrict__ qk, u16* __restrict__ kth) {
  __shared__ u16 tT[64 * 64];  // tT[d][l] swizzled: byte = d*128 + (2l ^ 16*(d>>3))
  char* base = (char*)tT;
  const int t = threadIdx.x;
  const int bid = blockIdx.x;
  const int lt = bid & 31, n = (bid >> 5) & 15, b = bid >> 9;
#pragma unroll
  for (int rr = 0; rr < 2; rr++) {
    const int l = rr * 32 + (t >> 3);
    const int d0 = (t & 7) * 8;
    us8 v = *(const us8*)(qk + ((size_t)(b * 2048 + lt * 64 + l)) * 2048 + 1024 + n * 64 + d0);
#pragma unroll
    for (int j = 0; j < 8; j++) {
      const int d = d0 + j;
      *(u16*)(base + d * 128 + ((2 * l) ^ (16 * (d >> 3)))) = v[j];
    }
  }
  __syncthreads();
  const int w = t >> 6, lane = t & 63;
#pragma unroll
  for (int rr = 0; rr < 2; rr++) {
    const int d = rr * 32 + w * 8 + (lane >> 3);
    const int l = (lane & 7) * 8;
    us8 v = *(const us8*)(base + d * 128 + ((2 * l) ^ (16 * (d >> 3))));
    *(us8*)(kth + ((size_t)((b * 16 + n) * 64 + d)) * 2048 + lt * 64 + l) = v;
  }
}

// ---------------- GEMM ----------------
// C[M,N] = A[M,K] @ B[K,N], A bf16 row-major, BT = B^T bf16 (N x K).
// BM=128, BK=32, BN in {128,64}. 4 waves: BN=128 -> 2x2 of 64x64; BN=64 -> 2x2 of 64x32.
// MODE 0: ob = acc (bf16)
// MODE 2: of = acc + res (f32)
// MODE 3: ob = gelu(acc + bias) (bf16)
// MODE 4: of = acc + bias + res (f32)
template <int MODE, int BN>
__global__ __launch_bounds__(256) void gemm128(
    const u16* __restrict__ A, const u16* __restrict__ BT,
    int M, int N, int K,
    u16* __restrict__ ob, float* __restrict__ of,
    const float* __restrict__ res, const float* __restrict__ bias) {
  constexpr int NJ = BN / 32;          // col frags per wave
  constexpr int WCC = BN / 2;          // cols per wave
  __shared__ u16 As[4096];
  __shared__ u16 Bs[BN * 32];
  const int t = threadIdx.x;
  const int nbm = M >> 7;
  const int nblk = nbm * (N / BN);
  int bid = blockIdx.x;
  bid = (bid & 7) * (nblk >> 3) + (bid >> 3);  // XCD-chunked swizzle (nblk % 8 == 0)
  const int bm = bid % nbm;
  const int bn = bid / nbm;
  const int m0 = bm << 7, n0 = bn * BN;
  const int w = t >> 6, lane = t & 63;
  const int wr = w >> 1, wc = w & 1;
  const int lr = lane & 15, lk = (lane >> 4) << 3, lq = (lane >> 4) << 2;

  const u16* ap = A + (size_t)(m0 + (t >> 2)) * K + ((t & 3) << 3);
  const u16* bp = BT + (size_t)(n0 + (t >> 2)) * K + ((t & 3) << 3);
  u16* asd = &As[t << 3];
  u16* bsd = &Bs[t << 3];
  const size_t half = (size_t)64 * K;

  f32x4 acc[4][NJ];
#pragma unroll
  for (int i = 0; i < 4; i++)
#pragma unroll
    for (int j = 0; j < NJ; j++) acc[i][j] = (f32x4){0.f, 0.f, 0.f, 0.f};

  for (int k0 = 0; k0 < K; k0 += 32) {
    gload_lds16(ap + k0, asd);
    gload_lds16(ap + half + k0, asd + 2048);
    gload_lds16(bp + k0, bsd);
    if constexpr (BN == 128) gload_lds16(bp + half + k0, bsd + 2048);
    __syncthreads();
    bf16x8 af[4], bfr[NJ];
#pragma unroll
    for (int i = 0; i < 4; i++) af[i] = ld_bf8(&As[(wr * 64 + i * 16 + lr) * 32 + lk]);
#pragma unroll
    for (int j = 0; j < NJ; j++) bfr[j] = ld_bf8(&Bs[(wc * WCC + j * 16 + lr) * 32 + lk]);
#pragma unroll
    for (int i = 0; i < 4; i++)
#pragma unroll
      for (int j = 0; j < NJ; j++) acc[i][j] = mfma16(af[i], bfr[j], acc[i][j]);
    __syncthreads();
  }

#pragma unroll
  for (int i = 0; i < 4; i++) {
    const int r0 = m0 + wr * 64 + i * 16 + lq;
#pragma unroll
    for (int j = 0; j < NJ; j++) {
      const int c = n0 + wc * WCC + j * 16 + lr;
      if constexpr (MODE == 0) {
#pragma unroll
        for (int q = 0; q < 4; q++) ob[(size_t)(r0 + q) * N + c] = f2bf(acc[i][j][q]);
      } else if constexpr (MODE == 2) {
#pragma unroll
        for (int q = 0; q < 4; q++) {
          const size_t idx = (size_t)(r0 + q) * N + c;
          of[idx] = acc[i][j][q] + res[idx];
        }
      } else if constexpr (MODE == 3) {
        const float bv = bias[c];
#pragma unroll
        for (int q = 0; q < 4; q++) {
          float u = acc[i][j][q] + bv;
          float gl = 0.5f * u * (1.f + erff(u * 0.70710678118f));
          ob[(size_t)(r0 + q) * N + c] = f2bf(gl);
        }
      } else {
        const float bv = bias[c];
#pragma unroll
        for (int q = 0; q < 4; q++) {
          const size_t idx = (size_t)(r0 + q) * N + c;
          of[idx] = acc[i][j][q] + bv + res[idx];
        }
      }
    }
  }
}

// ---------------- attention ----------------
// qk: [b][l][2048]  (cols 0..1023 = q head-major n*64+d, pre-scaled by 0.125*log2e;
//                    cols 1024..2047 = k head-major)
// kth: [b][n][d][l]  ("V" == K per source bug)
// out ctxh: [b][l][n*64+d] bf16
__global__ __launch_bounds__(256) void attn_kernel(
    const u16* __restrict__ qk, const u16* __restrict__ kth, u16* __restrict__ ctxh) {
  __shared__ u16 plds[4][1024];  // per-wave 16x64 P tile, XOR-swizzled
  const int t = threadIdx.x, w = t >> 6, lane = t & 63;
  const int lr = lane & 15, lg = lane >> 4;
  const int lk = lg << 3;
  int bid = blockIdx.x;
  bid = (bid & 7) * 128 + (bid >> 3);  // XCD-chunked swizzle: contiguous heads per XCD
  const int bq = bid & 31, hn = (bid >> 5) & 15, b = bid >> 9;
  const int l0 = bq * 64 + w * 16;
  const u16* qrow = qk + ((size_t)(b * 2048 + l0 + lr)) * 2048 + hn * 64;
  const u16* kbase = qk + (size_t)b * 2048 * 2048 + 1024 + hn * 64;
  const u16* ktb = kth + ((size_t)(b * 16 + hn)) * 64 * 2048;
  char* pb = (char*)&plds[w][0];

  bf16x8 qf[2];
  qf[0] = ld_bf8(qrow + lk);
  qf[1] = ld_bf8(qrow + 32 + lk);

  float mrow = -1e30f, lrow = 0.f;
  f32x4 o[4];
#pragma unroll
  for (int dj = 0; dj < 4; dj++) o[dj] = (f32x4){0.f, 0.f, 0.f, 0.f};

  const int bcast = (lane & 48) >> 2;  // 4*lg: base src lane for row broadcast

  for (int m0 = 0; m0 < 2048; m0 += 64) {
    // swapped QK^T: s[mj][reg] = S[key=16mj+4lg+reg][q=lr]
    f32x4 s[4];
#pragma unroll
    for (int mj = 0; mj < 4; mj++) s[mj] = (f32x4){0.f, 0.f, 0.f, 0.f};
#pragma unroll
    for (int mj = 0; mj < 4; mj++) {
      const u16* kr = kbase + (size_t)(m0 + mj * 16 + lr) * 2048 + lk;
      bf16x8 kf0 = ld_bf8(kr);
      bf16x8 kf1 = ld_bf8(kr + 32);
      s[mj] = mfma16(kf0, qf[0], s[mj]);
      s[mj] = mfma16(kf1, qf[1], s[mj]);
    }
    // row max: 16 in-register + 2 shfl (lanes with same lr share the row)
    float tm = s[0][0];
#pragma unroll
    for (int mj = 0; mj < 4; mj++)
#pragma unroll
      for (int q = 0; q < 4; q++) tm = fmaxf(tm, s[mj][q]);
    tm = fmaxf(tm, __shfl_xor(tm, 16));
    tm = fmaxf(tm, __shfl_xor(tm, 32));
    const float mnew = fmaxf(mrow, tm);
    const float al = fast_exp2(mrow - mnew);
    float p[4][4];
    float ts = 0.f;
#pragma unroll
    for (int mj = 0; mj < 4; mj++)
#pragma unroll
      for (int q = 0; q < 4; q++) {
        p[mj][q] = fast_exp2(s[mj][q] - mnew);
        ts += p[mj][q];
      }
    ts += __shfl_xor(ts, 16);
    ts += __shfl_xor(ts, 32);
    lrow = lrow * al + ts;
    mrow = mnew;
    // rescale o: o-row = 4*lg + reg; al lives on lane with lr == that row
    float albc[4];
#pragma unroll
    for (int q = 0; q < 4; q++) albc[q] = __shfl(al, bcast + q);
#pragma unroll
    for (int dj = 0; dj < 4; dj++)
#pragma unroll
      for (int q = 0; q < 4; q++) o[dj][q] *= albc[q];
    // P: D-layout -> A-layout via per-wave swizzled LDS
#pragma unroll
    for (int mj = 0; mj < 4; mj++) {
      u32 w0 = (u32)f2bf(p[mj][0]) | ((u32)f2bf(p[mj][1]) << 16);
      u32 w1 = (u32)f2bf(p[mj][2]) | ((u32)f2bf(p[mj][3]) << 16);
      uint2 pk2 = make_uint2(w0, w1);
      *(uint2*)(pb + ((lr * 128 + 32 * mj + 8 * lg) ^ ((lr & 3) << 4))) = pk2;
    }
    bf16x8 pa[2];
#pragma unroll
    for (int kk = 0; kk < 2; kk++)
      pa[kk] = __builtin_bit_cast(
          bf16x8, *(const us8*)(pb + ((lr * 128 + 64 * kk + 16 * lg) ^ ((lr & 3) << 4))));
    // PV: o += P @ K   (B-operand from kth)
#pragma unroll
    for (int dj = 0; dj < 4; dj++) {
      const u16* kt = ktb + (size_t)(dj * 16 + lr) * 2048 + m0 + lk;
      bf16x8 v0 = ld_bf8(kt);
      bf16x8 v1 = ld_bf8(kt + 32);
      o[dj] = mfma16(pa[0], v0, o[dj]);
      o[dj] = mfma16(pa[1], v1, o[dj]);
    }
  }

  const float inv = 1.f / lrow;
  float invbc[4];
#pragma unroll
  for (int q = 0; q < 4; q++) invbc[q] = __shfl(inv, bcast + q);
#pragma unroll
  for (int q = 0; q < 4; q++) {
    const int ll = l0 + 4 * lg + q;
#pragma unroll
    for (int dj = 0; dj < 4; dj++) {
      ctxh[((size_t)(b * 2048 + ll)) * 1024 + hn * 64 + dj * 16 + lr] =
          f2bf(o[dj][q] * invbc[q]);
    }
  }
}

// ---------------- layernorm ----------------
__global__ __launch_bounds__(256) void ln_kernel(
    const float* __restrict__ in, const float* __restrict__ gamma,
    const float* __restrict__ beta, float* __restrict__ o32, u16* __restrict__ o16) {
  __shared__ float red[8];
  const int row = blockIdx.x, t = threadIdx.x;
  const float4 v = ((const float4*)(in + (size_t)row * 1024))[t];
  float s = v.x + v.y + v.z + v.w;
  float ss = v.x * v.x + v.y * v.y + v.z * v.z + v.w * v.w;
#pragma unroll
  for (int off = 1; off < 64; off <<= 1) {
    s += __shfl_xor(s, off);
    ss += __shfl_xor(ss, off);
  }
  if ((t & 63) == 0) { red[t >> 6] = s; red[4 + (t >> 6)] = ss; }
  __syncthreads();
  const float st = red[0] + red[1] + red[2] + red[3];
  const float sst = red[4] + red[5] + red[6] + red[7];
  const float mean = st * (1.f / 1024.f);
  const float var = sst * (1.f / 1024.f) - mean * mean;
  const float rs = rsqrtf(var + 1e-5f);
  const float4 gv = ((const float4*)gamma)[t];
  const float4 bv = ((const float4*)beta)[t];
  float4 ov;
  ov.x = (v.x - mean) * rs * gv.x + bv.x;
  ov.y = (v.y - mean) * rs * gv.y + bv.y;
  ov.z = (v.z - mean) * rs * gv.z + bv.z;
  ov.w = (v.w - mean) * rs * gv.w + bv.w;
  ((float4*)(o32 + (size_t)row * 1024))[t] = ov;
  if (o16) {
    us4 h;
    h[0] = f2bf(ov.x); h[1] = f2bf(ov.y); h[2] = f2bf(ov.z); h[3] = f2bf(ov.w);
    *(us4*)(o16 + (size_t)row * 1024 + t * 4) = h;
  }
}

// ---------------- launch ----------------
extern "C" void kernel_launch(void* const* d_in, const int* in_sizes, int n_in,
                              void* d_out, int out_size, void* d_ws, size_t ws_size,
                              hipStream_t stream) {
  const float* x   = (const float*)d_in[0];
  const float* wq  = (const float*)d_in[1];
  const float* wk  = (const float*)d_in[2];
  const float* wo  = (const float*)d_in[3];
  const float* g1  = (const float*)d_in[4];
  const float* b1  = (const float*)d_in[5];
  const float* w1  = (const float*)d_in[6];
  const float* bb1 = (const float*)d_in[7];
  const float* w2  = (const float*)d_in[8];
  const float* bb2 = (const float*)d_in[9];
  const float* g2  = (const float*)d_in[10];
  const float* b2  = (const float*)d_in[11];

  char* ws = (char*)d_ws;
  const size_t MB = 1ull << 20;
  u16* xb    = (u16*)(ws + 0 * MB);    // 8 MB
  u16* qk    = (u16*)(ws + 8 * MB);    // 16 MB  [b][l][2048]
  u16* kthp  = (u16*)(ws + 24 * MB);   // 8 MB   [b][n][d][l]
  u16* ctxh  = (u16*)(ws + 32 * MB);   // 8 MB   [b][l][n*64+d]
  u16* tbuf  = (u16*)(ws + 8 * MB);    // 32 MB  overlay (dead qk/kth/ctxh)
  float* rbuf = (float*)(ws + 40 * MB);   // 16 MB
  float* hbuf = (float*)(ws + 56 * MB);   // 16 MB
  u16* hb    = (u16*)(ws + 72 * MB);   // 8 MB
  u16* wqkT  = (u16*)(ws + 80 * MB);   // 4 MB  [2048][1024]
  u16* woT   = (u16*)(ws + 84 * MB);   // 2 MB
  u16* w1T   = (u16*)(ws + 86 * MB);   // 8 MB
  u16* w2T   = (u16*)(ws + 94 * MB);   // 8 MB  (end 102 MB)

  // prep: x -> bf16; weights -> B^T bf16 with head-major permutes folded in
  conv_bf16_kernel<<<1024, 256, 0, stream>>>(x, xb, 1048576);
  // q scale folds 1/sqrt(64) and log2(e) (attn uses exp2)
  transpose_bf16_kernel<1><<<1024, 256, 0, stream>>>(wq, wqkT, 1024, 1024, 0.125f * 1.44269504089f);
  transpose_bf16_kernel<1><<<1024, 256, 0, stream>>>(wk, wqkT + (size_t)1024 * 1024, 1024, 1024, 1.0f);
  transpose_bf16_kernel<2><<<1024, 256, 0, stream>>>(wo, woT, 1024, 1024, 1.0f);
  transpose_bf16_kernel<0><<<32 * 128, 256, 0, stream>>>(w1, w1T, 1024, 4096, 1.0f);
  transpose_bf16_kernel<0><<<128 * 32, 256, 0, stream>>>(w2, w2T, 4096, 1024, 1.0f);

  // fused q+k projection: [4096,1024] @ [1024,2048] -> qk
  gemm128<0, 128><<<32 * 16, 256, 0, stream>>>(xb, wqkT, 4096, 2048, 1024, qk, nullptr, nullptr, nullptr);
  // k head-transpose for the PV B-operand
  khead_transpose<<<1024, 256, 0, stream>>>(qk, kthp);

  // attention (V := K per source bug)
  attn_kernel<<<1024, 256, 0, stream>>>(qk, kthp, ctxh);

  // ctx @ wo + x -> rbuf ; LN1 -> hbuf (f32) + hb (bf16)
  gemm128<2, 64><<<32 * 16, 256, 0, stream>>>(ctxh, woT, 4096, 1024, 1024, nullptr, rbuf, x, nullptr);
  ln_kernel<<<4096, 256, 0, stream>>>(rbuf, g1, b1, hbuf, hb);

  // FFN
  gemm128<3, 128><<<32 * 32, 256, 0, stream>>>(hb, w1T, 4096, 4096, 1024, tbuf, nullptr, nullptr, bb1);
  gemm128<4, 64><<<32 * 16, 256, 0, stream>>>(tbuf, w2T, 4096, 1024, 4096, nullptr, rbuf, hbuf, bb2);
  ln_kernel<<<4096, 256, 0, stream>>>(rbuf, g2, b2, (float*)d_out, nullptr);
}

// Round 4
// 309.377 us; speedup vs baseline: 1.5287x; 1.5287x over previous
//
#include <hip/hip_runtime.h>
#include <math.h>

typedef unsigned short u16;
typedef unsigned int u32;
typedef __bf16 bf16x8 __attribute__((ext_vector_type(8)));
typedef unsigned short us8 __attribute__((ext_vector_type(8)));
typedef unsigned short us4 __attribute__((ext_vector_type(4)));
typedef float f32x4 __attribute__((ext_vector_type(4)));

#define DEV __device__ __forceinline__

DEV float fast_exp2(float x) { return __builtin_amdgcn_exp2f(x); }

DEV u16 f2bf(float f) {
  __bf16 h = (__bf16)f;  // native v_cvt (RNE); pairs fuse to v_cvt_pk_bf16_f32
  return __builtin_bit_cast(u16, h);
}

DEV bf16x8 ld_bf8(const u16* p) { return __builtin_bit_cast(bf16x8, *(const us8*)p); }

DEV void gload_lds16(const u16* g, u16* l) {
  __builtin_amdgcn_global_load_lds((const __attribute__((address_space(1))) void*)g,
                                   (__attribute__((address_space(3))) void*)l, 16, 0, 0);
}

DEV f32x4 mfma16(bf16x8 a, bf16x8 b, f32x4 c) {
  return __builtin_amdgcn_mfma_f32_16x16x32_bf16(a, b, c, 0, 0, 0);
}

// ---------------- prep kernels ----------------

__global__ void conv_bf16_kernel(const float* __restrict__ in, u16* __restrict__ out, int n4) {
  const int stride = gridDim.x * blockDim.x;
  for (int i = blockIdx.x * blockDim.x + threadIdx.x; i < n4; i += stride) {
    float4 v = ((const float4*)in)[i];
    us4 h; h[0] = f2bf(v.x); h[1] = f2bf(v.y); h[2] = f2bf(v.z); h[3] = f2bf(v.w);
    ((us4*)out)[i] = h;
  }
}

// in: K x N f32 (row-major) -> out: N x K bf16 (B^T), times scale.
// P=0 plain; P=1 permute OUT row c' = ((c&15)<<6)|(c>>4) (head-major q/k, N==1024);
// P=2 gather IN row  src  = ((r&63)<<4)|(r>>6)           (wo: K index head-major, K==1024)
template <int P>
__global__ __launch_bounds__(256) void transpose_bf16_kernel(
    const float* __restrict__ in, u16* __restrict__ out, int K, int N, float scale) {
  __shared__ float tile[32][33];
  const int nbk = K >> 5;
  const int bk = blockIdx.x % nbk, bn = blockIdx.x / nbk;
  const int r0 = bk << 5, c0 = bn << 5;
  const int t = threadIdx.x;
  {
    const int r = t >> 3, c4 = (t & 7) << 2;
    int sr = r0 + r;
    if constexpr (P == 2) sr = ((sr & 63) << 4) | (sr >> 6);
    const float4 v = *(const float4*)(in + (size_t)sr * N + c0 + c4);
    tile[r][c4] = v.x; tile[r][c4 + 1] = v.y; tile[r][c4 + 2] = v.z; tile[r][c4 + 3] = v.w;
  }
  __syncthreads();
  {
    const int oc = t >> 3, r4 = (t & 7) << 2;
    int orow = c0 + oc;
    if constexpr (P == 1) orow = ((orow & 15) << 6) | (orow >> 4);
    us4 h;
#pragma unroll
    for (int j = 0; j < 4; j++) h[j] = f2bf(tile[r4 + j][oc] * scale);
    *(us4*)(out + (size_t)orow * K + r0 + r4) = h;
  }
}

// k half of qk [b][l][1024 + n*64 + d] -> kth [b][n][d][l]
__global__ __launch_bounds__(256) void khead_transpose(
    const u16* __restrict__ qk, u16* __restrict__ kth) {
  __shared__ u16 tT[64 * 64];  // tT[d][l] swizzled: byte = d*128 + (2l ^ 16*(d>>3))
  char* base = (char*)tT;
  const int t = threadIdx.x;
  const int bid = blockIdx.x;
  const int lt = bid & 31, n = (bid >> 5) & 15, b = bid >> 9;
#pragma unroll
  for (int rr = 0; rr < 2; rr++) {
    const int l = rr * 32 + (t >> 3);
    const int d0 = (t & 7) * 8;
    us8 v = *(const us8*)(qk + ((size_t)(b * 2048 + lt * 64 + l)) * 2048 + 1024 + n * 64 + d0);
#pragma unroll
    for (int j = 0; j < 8; j++) {
      const int d = d0 + j;
      *(u16*)(base + d * 128 + ((2 * l) ^ (16 * (d >> 3)))) = v[j];
    }
  }
  __syncthreads();
  const int w = t >> 6, lane = t & 63;
#pragma unroll
  for (int rr = 0; rr < 2; rr++) {
    const int d = rr * 32 + w * 8 + (lane >> 3);
    const int l = (lane & 7) * 8;
    us8 v = *(const us8*)(base + d * 128 + ((2 * l) ^ (16 * (d >> 3))));
    *(us8*)(kth + ((size_t)((b * 16 + n) * 64 + d)) * 2048 + lt * 64 + l) = v;
  }
}

// ---------------- GEMM ----------------
// C[M,N] = A[M,K] @ B[K,N], A bf16 row-major, BT = B^T bf16 (N x K).
// BM=128, BK=32, BN in {128,64}. 4 waves: BN=128 -> 2x2 of 64x64; BN=64 -> 2x2 of 64x32.
// MODE 0: ob = acc (bf16)
// MODE 2: of = acc + res (f32)
// MODE 3: ob = gelu(acc + bias) (bf16)
// MODE 4: of = acc + bias + res (f32)
template <int MODE, int BN>
__global__ __launch_bounds__(256) void gemm128(
    const u16* __restrict__ A, const u16* __restrict__ BT,
    int M, int N, int K,
    u16* __restrict__ ob, float* __restrict__ of,
    const float* __restrict__ res, const float* __restrict__ bias) {
  constexpr int NJ = BN / 32;          // col frags per wave
  constexpr int WCC = BN / 2;          // cols per wave
  __shared__ u16 As[4096];
  __shared__ u16 Bs[BN * 32];
  const int t = threadIdx.x;
  const int nbm = M >> 7;
  const int nblk = nbm * (N / BN);
  int bid = blockIdx.x;
  bid = (bid & 7) * (nblk >> 3) + (bid >> 3);  // XCD-chunked swizzle (nblk % 8 == 0)
  const int bm = bid % nbm;
  const int bn = bid / nbm;
  const int m0 = bm << 7, n0 = bn * BN;
  const int w = t >> 6, lane = t & 63;
  const int wr = w >> 1, wc = w & 1;
  const int lr = lane & 15, lk = (lane >> 4) << 3, lq = (lane >> 4) << 2;

  const u16* ap = A + (size_t)(m0 + (t >> 2)) * K + ((t & 3) << 3);
  const u16* bp = BT + (size_t)(n0 + (t >> 2)) * K + ((t & 3) << 3);
  u16* asd = &As[t << 3];
  u16* bsd = &Bs[t << 3];
  const size_t half = (size_t)64 * K;

  f32x4 acc[4][NJ];
#pragma unroll
  for (int i = 0; i < 4; i++)
#pragma unroll
    for (int j = 0; j < NJ; j++) acc[i][j] = (f32x4){0.f, 0.f, 0.f, 0.f};

  for (int k0 = 0; k0 < K; k0 += 32) {
    gload_lds16(ap + k0, asd);
    gload_lds16(ap + half + k0, asd + 2048);
    gload_lds16(bp + k0, bsd);
    if constexpr (BN == 128) gload_lds16(bp + half + k0, bsd + 2048);
    __syncthreads();
    bf16x8 af[4], bfr[NJ];
#pragma unroll
    for (int i = 0; i < 4; i++) af[i] = ld_bf8(&As[(wr * 64 + i * 16 + lr) * 32 + lk]);
#pragma unroll
    for (int j = 0; j < NJ; j++) bfr[j] = ld_bf8(&Bs[(wc * WCC + j * 16 + lr) * 32 + lk]);
#pragma unroll
    for (int i = 0; i < 4; i++)
#pragma unroll
      for (int j = 0; j < NJ; j++) acc[i][j] = mfma16(af[i], bfr[j], acc[i][j]);
    __syncthreads();
  }

#pragma unroll
  for (int i = 0; i < 4; i++) {
    const int r0 = m0 + wr * 64 + i * 16 + lq;
#pragma unroll
    for (int j = 0; j < NJ; j++) {
      const int c = n0 + wc * WCC + j * 16 + lr;
      if constexpr (MODE == 0) {
#pragma unroll
        for (int q = 0; q < 4; q++) ob[(size_t)(r0 + q) * N + c] = f2bf(acc[i][j][q]);
      } else if constexpr (MODE == 2) {
#pragma unroll
        for (int q = 0; q < 4; q++) {
          const size_t idx = (size_t)(r0 + q) * N + c;
          of[idx] = acc[i][j][q] + res[idx];
        }
      } else if constexpr (MODE == 3) {
        const float bv = bias[c];
#pragma unroll
        for (int q = 0; q < 4; q++) {
          float u = acc[i][j][q] + bv;
          float gl = 0.5f * u * (1.f + erff(u * 0.70710678118f));
          ob[(size_t)(r0 + q) * N + c] = f2bf(gl);
        }
      } else {
        const float bv = bias[c];
#pragma unroll
        for (int q = 0; q < 4; q++) {
          const size_t idx = (size_t)(r0 + q) * N + c;
          of[idx] = acc[i][j][q] + bv + res[idx];
        }
      }
    }
  }
}

// ---------------- attention ----------------
// qk: [b][l][2048]  (cols 0..1023 = q head-major n*64+d, pre-scaled by 0.125*log2e;
//                    cols 1024..2047 = k head-major)
// kth: [b][n][d][l]  ("V" == K per source bug)
// out ctxh: [b][l][n*64+d] bf16
// Block: 4 waves x 32 q-rows = 128 q-rows of one head. K/Kt tiles (64 keys) staged
// in LDS (double-buffered, global_load_lds w/ pre-swizzled source), XOR-swizzle
// (row&7)<<4 on all 128B-row LDS reads. Swapped QK^T; online softmax w/ defer-max.
__global__ __launch_bounds__(256, 2) void attn_kernel(
    const u16* __restrict__ qk, const u16* __restrict__ kth, u16* __restrict__ ctxh) {
  __shared__ u16 KsB[2][4096];   // [buf][key 0..63][d-seg swizzled]  8KB each
  __shared__ u16 KtsB[2][4096];  // [buf][d 0..63][key-seg swizzled]  8KB each
  __shared__ u16 Plds[4][2048];  // per-wave P: 2 frags x 16 rows x 128B
  const int t = threadIdx.x, w = t >> 6, lane = t & 63;
  const int lr = lane & 15, lg = lane >> 4;
  int bid = blockIdx.x;
  bid = (bid & 7) * 64 + (bid >> 3);  // XCD-chunked swizzle (512 blocks)
  const int qb = bid & 15, hn = (bid >> 4) & 15, b = bid >> 8;
  const int lw = qb * 128 + w * 32;
  const u16* ksrc = qk + (size_t)b * 2048 * 2048 + 1024 + hn * 64;  // K rows
  const u16* ktb = kth + ((size_t)(b * 16 + hn)) * 64 * 2048;       // Kt rows
  char* pb = (char*)&Plds[w][0];
  const int swz = (lr & 7) << 4;

#define STAGE_KV(buf, m0s)                                                    \
  {                                                                           \
    _Pragma("unroll") for (int i_ = 0; i_ < 2; i_++) {                        \
      const int s_ = t + 256 * i_;                                            \
      const int row_ = s_ >> 3;                                               \
      const int c_ = (s_ & 7) ^ (row_ & 7);                                   \
      gload_lds16(ksrc + (size_t)((m0s) + row_) * 2048 + c_ * 8,              \
                  &KsB[buf][s_ * 8]);                                         \
      gload_lds16(ktb + (size_t)row_ * 2048 + (m0s) + c_ * 8,                 \
                  &KtsB[buf][s_ * 8]);                                        \
    }                                                                         \
  }

  // Q fragments (B-operand): qf[f][kk] = Q[lw+16f+lr][kk*32 + lg*8 ..]
  bf16x8 qf[2][2];
#pragma unroll
  for (int f = 0; f < 2; f++)
#pragma unroll
    for (int kk = 0; kk < 2; kk++)
      qf[f][kk] = ld_bf8(qk + (size_t)(b * 2048 + lw + 16 * f + lr) * 2048 + hn * 64 +
                         kk * 32 + lg * 8);

  float mrow[2] = {-1e30f, -1e30f}, lrow[2] = {0.f, 0.f};
  f32x4 o[2][4];
#pragma unroll
  for (int f = 0; f < 2; f++)
#pragma unroll
    for (int dj = 0; dj < 4; dj++) o[f][dj] = (f32x4){0.f, 0.f, 0.f, 0.f};

  STAGE_KV(0, 0);
  __syncthreads();

  for (int it = 0; it < 32; ++it) {
    const int buf = it & 1;
    if (it < 31) STAGE_KV(buf ^ 1, (it + 1) * 64);

    // QK^T (swapped): sc[f][mj][reg] = S[key=16mj+4lg+reg][q = 16f+lr]
    f32x4 sc[2][4];
#pragma unroll
    for (int f = 0; f < 2; f++)
#pragma unroll
      for (int mj = 0; mj < 4; mj++) sc[f][mj] = (f32x4){0.f, 0.f, 0.f, 0.f};
#pragma unroll
    for (int mj = 0; mj < 4; mj++) {
      const int krow = 16 * mj + lr;
      bf16x8 kf0 = ld_bf8(&KsB[buf][krow * 64 + ((lg ^ (krow & 7)) << 3)]);
      bf16x8 kf1 = ld_bf8(&KsB[buf][krow * 64 + (((4 + lg) ^ (krow & 7)) << 3)]);
#pragma unroll
      for (int f = 0; f < 2; f++) {
        sc[f][mj] = mfma16(kf0, qf[f][0], sc[f][mj]);
        sc[f][mj] = mfma16(kf1, qf[f][1], sc[f][mj]);
      }
    }

    // online softmax per frag (row = q = 16f+lr; 16 vals in-lane + 2 shfl)
#pragma unroll
    for (int f = 0; f < 2; f++) {
      float tm = fmaxf(fmaxf(sc[f][0][0], sc[f][0][1]), fmaxf(sc[f][0][2], sc[f][0][3]));
#pragma unroll
      for (int mj = 1; mj < 4; mj++)
        tm = fmaxf(tm, fmaxf(fmaxf(sc[f][mj][0], sc[f][mj][1]),
                             fmaxf(sc[f][mj][2], sc[f][mj][3])));
      tm = fmaxf(tm, __shfl_xor(tm, 16));
      tm = fmaxf(tm, __shfl_xor(tm, 32));
      if (!__all(tm <= mrow[f] + 8.f)) {  // defer-max (T13), exp2 domain
        const float mnew = fmaxf(mrow[f], tm);
        const float al = fast_exp2(mrow[f] - mnew);
        mrow[f] = mnew;
        lrow[f] *= al;
        float albc[4];
#pragma unroll
        for (int q = 0; q < 4; q++) albc[q] = __shfl(al, 4 * lg + q);
#pragma unroll
        for (int dj = 0; dj < 4; dj++)
#pragma unroll
          for (int q = 0; q < 4; q++) o[f][dj][q] *= albc[q];
      }
      float ts = 0.f;
      char* pf = pb + f * 2048;
#pragma unroll
      for (int mj = 0; mj < 4; mj++) {
        float p0 = fast_exp2(sc[f][mj][0] - mrow[f]);
        float p1 = fast_exp2(sc[f][mj][1] - mrow[f]);
        float p2 = fast_exp2(sc[f][mj][2] - mrow[f]);
        float p3 = fast_exp2(sc[f][mj][3] - mrow[f]);
        ts += (p0 + p1) + (p2 + p3);
        u32 w0 = (u32)f2bf(p0) | ((u32)f2bf(p1) << 16);
        u32 w1 = (u32)f2bf(p2) | ((u32)f2bf(p3) << 16);
        *(uint2*)(pf + ((lr * 128 + mj * 32 + lg * 8) ^ swz)) = make_uint2(w0, w1);
      }
      ts += __shfl_xor(ts, 16);
      ts += __shfl_xor(ts, 32);
      lrow[f] += ts;
    }

    // P A-frags (same-wave LDS roundtrip; compiler orders via lgkmcnt)
    bf16x8 pa[2][2];
#pragma unroll
    for (int f = 0; f < 2; f++)
#pragma unroll
      for (int kk = 0; kk < 2; kk++)
        pa[f][kk] = __builtin_bit_cast(
            bf16x8, *(const us8*)(pb + f * 2048 + ((lr * 128 + kk * 64 + lg * 16) ^ swz)));

    // PV: o += P @ V  (V == K; B-operand from Kt tile)
#pragma unroll
    for (int dj = 0; dj < 4; dj++) {
      const int vrow = dj * 16 + lr;
      bf16x8 v0 = ld_bf8(&KtsB[buf][vrow * 64 + ((lg ^ (vrow & 7)) << 3)]);
      bf16x8 v1 = ld_bf8(&KtsB[buf][vrow * 64 + (((4 + lg) ^ (vrow & 7)) << 3)]);
#pragma unroll
      for (int f = 0; f < 2; f++) {
        o[f][dj] = mfma16(pa[f][0], v0, o[f][dj]);
        o[f][dj] = mfma16(pa[f][1], v1, o[f][dj]);
      }
    }
    __syncthreads();
  }
#undef STAGE_KV

#pragma unroll
  for (int f = 0; f < 2; f++) {
    const float inv = 1.f / lrow[f];
    float invbc[4];
#pragma unroll
    for (int q = 0; q < 4; q++) invbc[q] = __shfl(inv, 4 * lg + q);
#pragma unroll
    for (int q = 0; q < 4; q++) {
      const int ll = lw + 16 * f + 4 * lg + q;
#pragma unroll
      for (int dj = 0; dj < 4; dj++) {
        ctxh[((size_t)(b * 2048 + ll)) * 1024 + hn * 64 + dj * 16 + lr] =
            f2bf(o[f][dj][q] * invbc[q]);
      }
    }
  }
}

// ---------------- layernorm ----------------
__global__ __launch_bounds__(256) void ln_kernel(
    const float* __restrict__ in, const float* __restrict__ gamma,
    const float* __restrict__ beta, float* __restrict__ o32, u16* __restrict__ o16) {
  __shared__ float red[8];
  const int row = blockIdx.x, t = threadIdx.x;
  const float4 v = ((const float4*)(in + (size_t)row * 1024))[t];
  float s = v.x + v.y + v.z + v.w;
  float ss = v.x * v.x + v.y * v.y + v.z * v.z + v.w * v.w;
#pragma unroll
  for (int off = 1; off < 64; off <<= 1) {
    s += __shfl_xor(s, off);
    ss += __shfl_xor(ss, off);
  }
  if ((t & 63) == 0) { red[t >> 6] = s; red[4 + (t >> 6)] = ss; }
  __syncthreads();
  const float st = red[0] + red[1] + red[2] + red[3];
  const float sst = red[4] + red[5] + red[6] + red[7];
  const float mean = st * (1.f / 1024.f);
  const float var = sst * (1.f / 1024.f) - mean * mean;
  const float rs = rsqrtf(var + 1e-5f);
  const float4 gv = ((const float4*)gamma)[t];
  const float4 bv = ((const float4*)beta)[t];
  float4 ov;
  ov.x = (v.x - mean) * rs * gv.x + bv.x;
  ov.y = (v.y - mean) * rs * gv.y + bv.y;
  ov.z = (v.z - mean) * rs * gv.z + bv.z;
  ov.w = (v.w - mean) * rs * gv.w + bv.w;
  ((float4*)(o32 + (size_t)row * 1024))[t] = ov;
  if (o16) {
    us4 h;
    h[0] = f2bf(ov.x); h[1] = f2bf(ov.y); h[2] = f2bf(ov.z); h[3] = f2bf(ov.w);
    *(us4*)(o16 + (size_t)row * 1024 + t * 4) = h;
  }
}

// ---------------- launch ----------------
extern "C" void kernel_launch(void* const* d_in, const int* in_sizes, int n_in,
                              void* d_out, int out_size, void* d_ws, size_t ws_size,
                              hipStream_t stream) {
  const float* x   = (const float*)d_in[0];
  const float* wq  = (const float*)d_in[1];
  const float* wk  = (const float*)d_in[2];
  const float* wo  = (const float*)d_in[3];
  const float* g1  = (const float*)d_in[4];
  const float* b1  = (const float*)d_in[5];
  const float* w1  = (const float*)d_in[6];
  const float* bb1 = (const float*)d_in[7];
  const float* w2  = (const float*)d_in[8];
  const float* bb2 = (const float*)d_in[9];
  const float* g2  = (const float*)d_in[10];
  const float* b2  = (const float*)d_in[11];

  char* ws = (char*)d_ws;
  const size_t MB = 1ull << 20;
  u16* xb    = (u16*)(ws + 0 * MB);    // 8 MB
  u16* qk    = (u16*)(ws + 8 * MB);    // 16 MB  [b][l][2048]
  u16* kthp  = (u16*)(ws + 24 * MB);   // 8 MB   [b][n][d][l]
  u16* ctxh  = (u16*)(ws + 32 * MB);   // 8 MB   [b][l][n*64+d]
  u16* tbuf  = (u16*)(ws + 8 * MB);    // 32 MB  overlay (dead qk/kth/ctxh)
  float* rbuf = (float*)(ws + 40 * MB);   // 16 MB
  float* hbuf = (float*)(ws + 56 * MB);   // 16 MB
  u16* hb    = (u16*)(ws + 72 * MB);   // 8 MB
  u16* wqkT  = (u16*)(ws + 80 * MB);   // 4 MB  [2048][1024]
  u16* woT   = (u16*)(ws + 84 * MB);   // 2 MB
  u16* w1T   = (u16*)(ws + 86 * MB);   // 8 MB
  u16* w2T   = (u16*)(ws + 94 * MB);   // 8 MB  (end 102 MB)

  // prep: x -> bf16; weights -> B^T bf16 with head-major permutes folded in
  conv_bf16_kernel<<<1024, 256, 0, stream>>>(x, xb, 1048576);
  // q scale folds 1/sqrt(64) and log2(e) (attn uses exp2)
  transpose_bf16_kernel<1><<<1024, 256, 0, stream>>>(wq, wqkT, 1024, 1024, 0.125f * 1.44269504089f);
  transpose_bf16_kernel<1><<<1024, 256, 0, stream>>>(wk, wqkT + (size_t)1024 * 1024, 1024, 1024, 1.0f);
  transpose_bf16_kernel<2><<<1024, 256, 0, stream>>>(wo, woT, 1024, 1024, 1.0f);
  transpose_bf16_kernel<0><<<32 * 128, 256, 0, stream>>>(w1, w1T, 1024, 4096, 1.0f);
  transpose_bf16_kernel<0><<<128 * 32, 256, 0, stream>>>(w2, w2T, 4096, 1024, 1.0f);

  // fused q+k projection: [4096,1024] @ [1024,2048] -> qk
  gemm128<0, 128><<<32 * 16, 256, 0, stream>>>(xb, wqkT, 4096, 2048, 1024, qk, nullptr, nullptr, nullptr);
  // k head-transpose for the PV B-operand
  khead_transpose<<<1024, 256, 0, stream>>>(qk, kthp);

  // attention (V := K per source bug)
  attn_kernel<<<512, 256, 0, stream>>>(qk, kthp, ctxh);

  // ctx @ wo + x -> rbuf ; LN1 -> hbuf (f32) + hb (bf16)
  gemm128<2, 64><<<32 * 16, 256, 0, stream>>>(ctxh, woT, 4096, 1024, 1024, nullptr, rbuf, x, nullptr);
  ln_kernel<<<4096, 256, 0, stream>>>(rbuf, g1, b1, hbuf, hb);

  // FFN
  gemm128<3, 128><<<32 * 32, 256, 0, stream>>>(hb, w1T, 4096, 4096, 1024, tbuf, nullptr, nullptr, bb1);
  gemm128<4, 64><<<32 * 16, 256, 0, stream>>>(tbuf, w2T, 4096, 1024, 4096, nullptr, rbuf, hbuf, bb2);
  ln_kernel<<<4096, 256, 0, stream>>>(rbuf, g2, b2, (float*)d_out, nullptr);
}

// Round 5
// 276.416 us; speedup vs baseline: 1.7109x; 1.1192x over previous
//
#include <hip/hip_runtime.h>
#include <math.h>

typedef unsigned short u16;
typedef unsigned int u32;
typedef __bf16 bf16x8 __attribute__((ext_vector_type(8)));
typedef unsigned short us8 __attribute__((ext_vector_type(8)));
typedef unsigned short us4 __attribute__((ext_vector_type(4)));
typedef float f32x4 __attribute__((ext_vector_type(4)));

#define DEV __device__ __forceinline__

DEV float fast_exp2(float x) { return __builtin_amdgcn_exp2f(x); }

DEV u16 f2bf(float f) {
  __bf16 h = (__bf16)f;  // native v_cvt (RNE); pairs fuse to v_cvt_pk_bf16_f32
  return __builtin_bit_cast(u16, h);
}

DEV bf16x8 ld_bf8(const u16* p) { return __builtin_bit_cast(bf16x8, *(const us8*)p); }

DEV void gload_lds16(const u16* g, u16* l) {
  __builtin_amdgcn_global_load_lds((const __attribute__((address_space(1))) void*)g,
                                   (__attribute__((address_space(3))) void*)l, 16, 0, 0);
}

DEV f32x4 mfma16(bf16x8 a, bf16x8 b, f32x4 c) {
  return __builtin_amdgcn_mfma_f32_16x16x32_bf16(a, b, c, 0, 0, 0);
}

// ---------------- prep kernels ----------------

__global__ void conv_bf16_kernel(const float* __restrict__ in, u16* __restrict__ out, int n4) {
  const int stride = gridDim.x * blockDim.x;
  for (int i = blockIdx.x * blockDim.x + threadIdx.x; i < n4; i += stride) {
    float4 v = ((const float4*)in)[i];
    us4 h; h[0] = f2bf(v.x); h[1] = f2bf(v.y); h[2] = f2bf(v.z); h[3] = f2bf(v.w);
    ((us4*)out)[i] = h;
  }
}

// in: K x N f32 (row-major) -> out: N x K bf16 (B^T), times scale.
// P=0 plain; P=1 permute OUT row c' = ((c&15)<<6)|(c>>4) (head-major q/k, N==1024);
// P=2 gather IN row  src  = ((r&63)<<4)|(r>>6)           (wo: K index head-major, K==1024)
template <int P>
__global__ __launch_bounds__(256) void transpose_bf16_kernel(
    const float* __restrict__ in, u16* __restrict__ out, int K, int N, float scale) {
  __shared__ float tile[32][33];
  const int nbk = K >> 5;
  const int bk = blockIdx.x % nbk, bn = blockIdx.x / nbk;
  const int r0 = bk << 5, c0 = bn << 5;
  const int t = threadIdx.x;
  {
    const int r = t >> 3, c4 = (t & 7) << 2;
    int sr = r0 + r;
    if constexpr (P == 2) sr = ((sr & 63) << 4) | (sr >> 6);
    const float4 v = *(const float4*)(in + (size_t)sr * N + c0 + c4);
    tile[r][c4] = v.x; tile[r][c4 + 1] = v.y; tile[r][c4 + 2] = v.z; tile[r][c4 + 3] = v.w;
  }
  __syncthreads();
  {
    const int oc = t >> 3, r4 = (t & 7) << 2;
    int orow = c0 + oc;
    if constexpr (P == 1) orow = ((orow & 15) << 6) | (orow >> 4);
    us4 h;
#pragma unroll
    for (int j = 0; j < 4; j++) h[j] = f2bf(tile[r4 + j][oc] * scale);
    *(us4*)(out + (size_t)orow * K + r0 + r4) = h;
  }
}

// k half of qk [b][l][1024 + n*64 + d] -> kth [b][n][d][l]
__global__ __launch_bounds__(256) void khead_transpose(
    const u16* __restrict__ qk, u16* __restrict__ kth) {
  __shared__ u16 tT[64 * 64];  // tT[d][l] swizzled: byte = d*128 + (2l ^ 16*(d>>3))
  char* base = (char*)tT;
  const int t = threadIdx.x;
  const int bid = blockIdx.x;
  const int lt = bid & 31, n = (bid >> 5) & 15, b = bid >> 9;
#pragma unroll
  for (int rr = 0; rr < 2; rr++) {
    const int l = rr * 32 + (t >> 3);
    const int d0 = (t & 7) * 8;
    us8 v = *(const us8*)(qk + ((size_t)(b * 2048 + lt * 64 + l)) * 2048 + 1024 + n * 64 + d0);
#pragma unroll
    for (int j = 0; j < 8; j++) {
      const int d = d0 + j;
      *(u16*)(base + d * 128 + ((2 * l) ^ (16 * (d >> 3)))) = v[j];
    }
  }
  __syncthreads();
  const int w = t >> 6, lane = t & 63;
#pragma unroll
  for (int rr = 0; rr < 2; rr++) {
    const int d = rr * 32 + w * 8 + (lane >> 3);
    const int l = (lane & 7) * 8;
    us8 v = *(const us8*)(base + d * 128 + ((2 * l) ^ (16 * (d >> 3))));
    *(us8*)(kth + ((size_t)((b * 16 + n) * 64 + d)) * 2048 + lt * 64 + l) = v;
  }
}

// ---------------- GEMM ----------------
// C[M,N] = A[M,K] @ B[K,N], A bf16 row-major, BT = B^T bf16 (N x K).
// BM=128, BK=32, BN in {128,64}; KS-way split-K (partials to of + ks*M*N).
// Double-buffered LDS, STAGE issued BEFORE compute (T3-minimum pipeline).
// Conflict swizzle: LDS seg ^= row&3 on both stage-source and reads (8->4-way).
// MODE 0: ob = acc (bf16)
// MODE 2: of = acc + res (f32)
// MODE 3: ob = gelu(acc + bias) (bf16)
// MODE 5: of[ks*M*N + idx] = acc (f32 partials)
template <int MODE, int BN, int KS>
__global__ __launch_bounds__(256) void gemm128(
    const u16* __restrict__ A, const u16* __restrict__ BT,
    int M, int N, int K,
    u16* __restrict__ ob, float* __restrict__ of,
    const float* __restrict__ res, const float* __restrict__ bias) {
  constexpr int NJ = BN / 32;          // col frags per wave
  constexpr int WCC = BN / 2;          // cols per wave
  __shared__ u16 As[2][4096];
  __shared__ u16 Bs[2][BN * 32];
  const int t = threadIdx.x;
  const int nbm = M >> 7;
  const int nblk = nbm * (N / BN) * KS;
  int bid = blockIdx.x;
  bid = (bid & 7) * (nblk >> 3) + (bid >> 3);  // XCD-chunked swizzle (nblk % 8 == 0)
  int ks = 0;
  if constexpr (KS > 1) { ks = bid % KS; bid /= KS; }
  const int bm = bid % nbm;
  const int bn = bid / nbm;
  const int m0 = bm << 7, n0 = bn * BN;
  const int kbeg = ks * (K / KS);
  const int KB = K / KS;
  const int w = t >> 6, lane = t & 63;
  const int wr = w >> 1, wc = w & 1;
  const int lr = lane & 15, lg = lane >> 4, lq = (lane >> 4) << 2;
  const int rsw = (lg ^ (lr & 3)) << 3;  // swizzled read seg (u16 units)

  const int srow = t >> 2;
  const int sseg = (t & 3) ^ (srow & 3);  // swizzled source seg
  const u16* ap = A + (size_t)(m0 + srow) * K + kbeg + sseg * 8;
  const u16* bp = BT + (size_t)(n0 + srow) * K + kbeg + sseg * 8;
  const size_t half = (size_t)64 * K;

#define STAGE(buf, k0)                                                 \
  {                                                                    \
    gload_lds16(ap + (k0), &As[buf][t << 3]);                          \
    gload_lds16(ap + half + (k0), &As[buf][(t << 3) + 2048]);          \
    gload_lds16(bp + (k0), &Bs[buf][t << 3]);                          \
    if constexpr (BN == 128)                                           \
      gload_lds16(bp + half + (k0), &Bs[buf][(t << 3) + 2048]);        \
  }

  f32x4 acc[4][NJ];
#pragma unroll
  for (int i = 0; i < 4; i++)
#pragma unroll
    for (int j = 0; j < NJ; j++) acc[i][j] = (f32x4){0.f, 0.f, 0.f, 0.f};

  STAGE(0, 0);
  __syncthreads();
  const int NI = KB >> 5;
  for (int it = 0; it < NI; ++it) {
    const int buf = it & 1;
    if (it + 1 < NI) STAGE(buf ^ 1, (it + 1) << 5);  // issue-early: hides under compute
    bf16x8 af[4], bfr[NJ];
#pragma unroll
    for (int i = 0; i < 4; i++)
      af[i] = ld_bf8(&As[buf][(wr * 64 + i * 16 + lr) * 32 + rsw]);
#pragma unroll
    for (int j = 0; j < NJ; j++)
      bfr[j] = ld_bf8(&Bs[buf][(wc * WCC + j * 16 + lr) * 32 + rsw]);
#pragma unroll
    for (int i = 0; i < 4; i++)
#pragma unroll
      for (int j = 0; j < NJ; j++) acc[i][j] = mfma16(af[i], bfr[j], acc[i][j]);
    __syncthreads();
  }
#undef STAGE

#pragma unroll
  for (int i = 0; i < 4; i++) {
    const int r0 = m0 + wr * 64 + i * 16 + lq;
#pragma unroll
    for (int j = 0; j < NJ; j++) {
      const int c = n0 + wc * WCC + j * 16 + lr;
      if constexpr (MODE == 0) {
#pragma unroll
        for (int q = 0; q < 4; q++) ob[(size_t)(r0 + q) * N + c] = f2bf(acc[i][j][q]);
      } else if constexpr (MODE == 2) {
#pragma unroll
        for (int q = 0; q < 4; q++) {
          const size_t idx = (size_t)(r0 + q) * N + c;
          of[idx] = acc[i][j][q] + res[idx];
        }
      } else if constexpr (MODE == 3) {
        const float bv = bias[c];
#pragma unroll
        for (int q = 0; q < 4; q++) {
          float u = acc[i][j][q] + bv;
          float gl = 0.5f * u * (1.f + erff(u * 0.70710678118f));
          ob[(size_t)(r0 + q) * N + c] = f2bf(gl);
        }
      } else {  // MODE 5: split-K partial
        const size_t ofs = (size_t)ks * M * N;
#pragma unroll
        for (int q = 0; q < 4; q++) {
          of[ofs + (size_t)(r0 + q) * N + c] = acc[i][j][q];
        }
      }
    }
  }
}

// ---------------- attention ----------------
// qk: [b][l][2048]  (cols 0..1023 = q head-major n*64+d, pre-scaled by 0.125*log2e;
//                    cols 1024..2047 = k head-major)
// kth: [b][n][d][l]  ("V" == K per source bug)
// out ctxh: [b][l][n*64+d] bf16
__global__ __launch_bounds__(256, 2) void attn_kernel(
    const u16* __restrict__ qk, const u16* __restrict__ kth, u16* __restrict__ ctxh) {
  __shared__ u16 KsB[2][4096];   // [buf][key 0..63][d-seg swizzled]  8KB each
  __shared__ u16 KtsB[2][4096];  // [buf][d 0..63][key-seg swizzled]  8KB each
  __shared__ u16 Plds[4][2048];  // per-wave P: 2 frags x 16 rows x 128B
  const int t = threadIdx.x, w = t >> 6, lane = t & 63;
  const int lr = lane & 15, lg = lane >> 4;
  int bid = blockIdx.x;
  bid = (bid & 7) * 64 + (bid >> 3);  // XCD-chunked swizzle (512 blocks)
  const int qb = bid & 15, hn = (bid >> 4) & 15, b = bid >> 8;
  const int lw = qb * 128 + w * 32;
  const u16* ksrc = qk + (size_t)b * 2048 * 2048 + 1024 + hn * 64;  // K rows
  const u16* ktb = kth + ((size_t)(b * 16 + hn)) * 64 * 2048;       // Kt rows
  char* pb = (char*)&Plds[w][0];
  const int swz = (lr & 7) << 4;

#define STAGE_KV(buf, m0s)                                                    \
  {                                                                           \
    _Pragma("unroll") for (int i_ = 0; i_ < 2; i_++) {                        \
      const int s_ = t + 256 * i_;                                            \
      const int row_ = s_ >> 3;                                               \
      const int c_ = (s_ & 7) ^ (row_ & 7);                                   \
      gload_lds16(ksrc + (size_t)((m0s) + row_) * 2048 + c_ * 8,              \
                  &KsB[buf][s_ * 8]);                                         \
      gload_lds16(ktb + (size_t)row_ * 2048 + (m0s) + c_ * 8,                 \
                  &KtsB[buf][s_ * 8]);                                        \
    }                                                                         \
  }

  // Q fragments (B-operand): qf[f][kk] = Q[lw+16f+lr][kk*32 + lg*8 ..]
  bf16x8 qf[2][2];
#pragma unroll
  for (int f = 0; f < 2; f++)
#pragma unroll
    for (int kk = 0; kk < 2; kk++)
      qf[f][kk] = ld_bf8(qk + (size_t)(b * 2048 + lw + 16 * f + lr) * 2048 + hn * 64 +
                         kk * 32 + lg * 8);

  float mrow[2] = {-1e30f, -1e30f}, lrow[2] = {0.f, 0.f};
  f32x4 o[2][4];
#pragma unroll
  for (int f = 0; f < 2; f++)
#pragma unroll
    for (int dj = 0; dj < 4; dj++) o[f][dj] = (f32x4){0.f, 0.f, 0.f, 0.f};

  STAGE_KV(0, 0);
  __syncthreads();

  for (int it = 0; it < 32; ++it) {
    const int buf = it & 1;
    if (it < 31) STAGE_KV(buf ^ 1, (it + 1) * 64);

    // QK^T (swapped): sc[f][mj][reg] = S[key=16mj+4lg+reg][q = 16f+lr]
    f32x4 sc[2][4];
#pragma unroll
    for (int f = 0; f < 2; f++)
#pragma unroll
      for (int mj = 0; mj < 4; mj++) sc[f][mj] = (f32x4){0.f, 0.f, 0.f, 0.f};
#pragma unroll
    for (int mj = 0; mj < 4; mj++) {
      const int krow = 16 * mj + lr;
      bf16x8 kf0 = ld_bf8(&KsB[buf][krow * 64 + ((lg ^ (krow & 7)) << 3)]);
      bf16x8 kf1 = ld_bf8(&KsB[buf][krow * 64 + (((4 + lg) ^ (krow & 7)) << 3)]);
#pragma unroll
      for (int f = 0; f < 2; f++) {
        sc[f][mj] = mfma16(kf0, qf[f][0], sc[f][mj]);
        sc[f][mj] = mfma16(kf1, qf[f][1], sc[f][mj]);
      }
    }

    // online softmax per frag (row = q = 16f+lr; 16 vals in-lane + 2 shfl)
#pragma unroll
    for (int f = 0; f < 2; f++) {
      float tm = fmaxf(fmaxf(sc[f][0][0], sc[f][0][1]), fmaxf(sc[f][0][2], sc[f][0][3]));
#pragma unroll
      for (int mj = 1; mj < 4; mj++)
        tm = fmaxf(tm, fmaxf(fmaxf(sc[f][mj][0], sc[f][mj][1]),
                             fmaxf(sc[f][mj][2], sc[f][mj][3])));
      tm = fmaxf(tm, __shfl_xor(tm, 16));
      tm = fmaxf(tm, __shfl_xor(tm, 32));
      if (!__all(tm <= mrow[f] + 8.f)) {  // defer-max (T13), exp2 domain
        const float mnew = fmaxf(mrow[f], tm);
        const float al = fast_exp2(mrow[f] - mnew);
        mrow[f] = mnew;
        lrow[f] *= al;
        float albc[4];
#pragma unroll
        for (int q = 0; q < 4; q++) albc[q] = __shfl(al, 4 * lg + q);
#pragma unroll
        for (int dj = 0; dj < 4; dj++)
#pragma unroll
          for (int q = 0; q < 4; q++) o[f][dj][q] *= albc[q];
      }
      float ts = 0.f;
      char* pf = pb + f * 2048;
#pragma unroll
      for (int mj = 0; mj < 4; mj++) {
        float p0 = fast_exp2(sc[f][mj][0] - mrow[f]);
        float p1 = fast_exp2(sc[f][mj][1] - mrow[f]);
        float p2 = fast_exp2(sc[f][mj][2] - mrow[f]);
        float p3 = fast_exp2(sc[f][mj][3] - mrow[f]);
        ts += (p0 + p1) + (p2 + p3);
        u32 w0 = (u32)f2bf(p0) | ((u32)f2bf(p1) << 16);
        u32 w1 = (u32)f2bf(p2) | ((u32)f2bf(p3) << 16);
        *(uint2*)(pf + ((lr * 128 + mj * 32 + lg * 8) ^ swz)) = make_uint2(w0, w1);
      }
      ts += __shfl_xor(ts, 16);
      ts += __shfl_xor(ts, 32);
      lrow[f] += ts;
    }

    // P A-frags (same-wave LDS roundtrip; compiler orders via lgkmcnt)
    bf16x8 pa[2][2];
#pragma unroll
    for (int f = 0; f < 2; f++)
#pragma unroll
      for (int kk = 0; kk < 2; kk++)
        pa[f][kk] = __builtin_bit_cast(
            bf16x8, *(const us8*)(pb + f * 2048 + ((lr * 128 + kk * 64 + lg * 16) ^ swz)));

    // PV: o += P @ V  (V == K; B-operand from Kt tile)
#pragma unroll
    for (int dj = 0; dj < 4; dj++) {
      const int vrow = dj * 16 + lr;
      bf16x8 v0 = ld_bf8(&KtsB[buf][vrow * 64 + ((lg ^ (vrow & 7)) << 3)]);
      bf16x8 v1 = ld_bf8(&KtsB[buf][vrow * 64 + (((4 + lg) ^ (vrow & 7)) << 3)]);
#pragma unroll
      for (int f = 0; f < 2; f++) {
        o[f][dj] = mfma16(pa[f][0], v0, o[f][dj]);
        o[f][dj] = mfma16(pa[f][1], v1, o[f][dj]);
      }
    }
    __syncthreads();
  }
#undef STAGE_KV

#pragma unroll
  for (int f = 0; f < 2; f++) {
    const float inv = 1.f / lrow[f];
    float invbc[4];
#pragma unroll
    for (int q = 0; q < 4; q++) invbc[q] = __shfl(inv, 4 * lg + q);
#pragma unroll
    for (int q = 0; q < 4; q++) {
      const int ll = lw + 16 * f + 4 * lg + q;
#pragma unroll
      for (int dj = 0; dj < 4; dj++) {
        ctxh[((size_t)(b * 2048 + ll)) * 1024 + hn * 64 + dj * 16 + lr] =
            f2bf(o[f][dj][q] * invbc[q]);
      }
    }
  }
}

// ---------------- layernorm ----------------
// V=0: val = in ;  V=1: val = in + in2 + res + bias (split-K reduce + bias + residual)
template <int V>
__global__ __launch_bounds__(256) void ln_kernel(
    const float* __restrict__ in, const float* __restrict__ in2,
    const float* __restrict__ res, const float* __restrict__ bias,
    const float* __restrict__ gamma, const float* __restrict__ beta,
    float* __restrict__ o32, u16* __restrict__ o16) {
  __shared__ float red[8];
  const int row = blockIdx.x, t = threadIdx.x;
  float4 v = ((const float4*)(in + (size_t)row * 1024))[t];
  if constexpr (V == 1) {
    const float4 v2 = ((const float4*)(in2 + (size_t)row * 1024))[t];
    const float4 vr = ((const float4*)(res + (size_t)row * 1024))[t];
    const float4 vb = ((const float4*)bias)[t];
    v.x += v2.x + vr.x + vb.x;
    v.y += v2.y + vr.y + vb.y;
    v.z += v2.z + vr.z + vb.z;
    v.w += v2.w + vr.w + vb.w;
  }
  float s = v.x + v.y + v.z + v.w;
  float ss = v.x * v.x + v.y * v.y + v.z * v.z + v.w * v.w;
#pragma unroll
  for (int off = 1; off < 64; off <<= 1) {
    s += __shfl_xor(s, off);
    ss += __shfl_xor(ss, off);
  }
  if ((t & 63) == 0) { red[t >> 6] = s; red[4 + (t >> 6)] = ss; }
  __syncthreads();
  const float st = red[0] + red[1] + red[2] + red[3];
  const float sst = red[4] + red[5] + red[6] + red[7];
  const float mean = st * (1.f / 1024.f);
  const float var = sst * (1.f / 1024.f) - mean * mean;
  const float rs = rsqrtf(var + 1e-5f);
  const float4 gv = ((const float4*)gamma)[t];
  const float4 bv = ((const float4*)beta)[t];
  float4 ov;
  ov.x = (v.x - mean) * rs * gv.x + bv.x;
  ov.y = (v.y - mean) * rs * gv.y + bv.y;
  ov.z = (v.z - mean) * rs * gv.z + bv.z;
  ov.w = (v.w - mean) * rs * gv.w + bv.w;
  ((float4*)(o32 + (size_t)row * 1024))[t] = ov;
  if (o16) {
    us4 h;
    h[0] = f2bf(ov.x); h[1] = f2bf(ov.y); h[2] = f2bf(ov.z); h[3] = f2bf(ov.w);
    *(us4*)(o16 + (size_t)row * 1024 + t * 4) = h;
  }
}

// ---------------- launch ----------------
extern "C" void kernel_launch(void* const* d_in, const int* in_sizes, int n_in,
                              void* d_out, int out_size, void* d_ws, size_t ws_size,
                              hipStream_t stream) {
  const float* x   = (const float*)d_in[0];
  const float* wq  = (const float*)d_in[1];
  const float* wk  = (const float*)d_in[2];
  const float* wo  = (const float*)d_in[3];
  const float* g1  = (const float*)d_in[4];
  const float* b1  = (const float*)d_in[5];
  const float* w1  = (const float*)d_in[6];
  const float* bb1 = (const float*)d_in[7];
  const float* w2  = (const float*)d_in[8];
  const float* bb2 = (const float*)d_in[9];
  const float* g2  = (const float*)d_in[10];
  const float* b2  = (const float*)d_in[11];

  char* ws = (char*)d_ws;
  const size_t MB = 1ull << 20;
  // arena (102 MB total, lifetimes disjoint where overlapped):
  u16* w2T   = (u16*)(ws + 0 * MB);    //  0-8   [prep -> w2 gemm]
  u16* w1T   = (u16*)(ws + 8 * MB);    //  8-16  [prep -> w1 gemm]
  u16* woT   = (u16*)(ws + 16 * MB);   // 16-18  [prep -> wo gemm]
  u16* wqkT  = (u16*)(ws + 18 * MB);   // 18-22  [prep -> qk gemm]
  u16* xb    = (u16*)(ws + 22 * MB);   // 22-30  [conv -> qk gemm]
  u16* qk    = (u16*)(ws + 30 * MB);   // 30-46  [qk gemm -> attn]
  u16* kthp  = (u16*)(ws + 46 * MB);   // 46-54  [khead -> attn]
  u16* ctxh  = (u16*)(ws + 54 * MB);   // 54-62  [attn -> wo gemm]
  float* rbuf = (float*)(ws + 62 * MB);  // 62-78  [wo gemm -> ln1]
  u16* hb    = (u16*)(ws + 78 * MB);   // 78-86  [ln1 -> w1 gemm]
  float* hbuf = (float*)(ws + 86 * MB);  // 86-102 [ln1 -> ln2]
  u16* tbuf  = (u16*)(ws + 18 * MB);   // 18-50  overlay [w1 -> w2] (wqkT/xb/qk/kth dead)
  float* rA   = (float*)(ws + 50 * MB);  // 50-82  overlay [w2 -> ln2] (ctxh/rbuf/hb dead)

  // prep: x -> bf16; weights -> B^T bf16 with head-major permutes folded in
  conv_bf16_kernel<<<1024, 256, 0, stream>>>(x, xb, 1048576);
  // q scale folds 1/sqrt(64) and log2(e) (attn uses exp2)
  transpose_bf16_kernel<1><<<1024, 256, 0, stream>>>(wq, wqkT, 1024, 1024, 0.125f * 1.44269504089f);
  transpose_bf16_kernel<1><<<1024, 256, 0, stream>>>(wk, wqkT + (size_t)1024 * 1024, 1024, 1024, 1.0f);
  transpose_bf16_kernel<2><<<1024, 256, 0, stream>>>(wo, woT, 1024, 1024, 1.0f);
  transpose_bf16_kernel<0><<<32 * 128, 256, 0, stream>>>(w1, w1T, 1024, 4096, 1.0f);
  transpose_bf16_kernel<0><<<128 * 32, 256, 0, stream>>>(w2, w2T, 4096, 1024, 1.0f);

  // fused q+k projection: [4096,1024] @ [1024,2048] -> qk
  gemm128<0, 128, 1><<<32 * 16, 256, 0, stream>>>(xb, wqkT, 4096, 2048, 1024, qk, nullptr, nullptr, nullptr);
  // k head-transpose for the PV B-operand
  khead_transpose<<<1024, 256, 0, stream>>>(qk, kthp);

  // attention (V := K per source bug)
  attn_kernel<<<512, 256, 0, stream>>>(qk, kthp, ctxh);

  // ctx @ wo + x -> rbuf ; LN1 -> hbuf (f32) + hb (bf16)
  gemm128<2, 64, 1><<<32 * 16, 256, 0, stream>>>(ctxh, woT, 4096, 1024, 1024, nullptr, rbuf, x, nullptr);
  ln_kernel<0><<<4096, 256, 0, stream>>>(rbuf, nullptr, nullptr, nullptr, g1, b1, hbuf, hb);

  // FFN
  gemm128<3, 128, 1><<<32 * 32, 256, 0, stream>>>(hb, w1T, 4096, 4096, 1024, tbuf, nullptr, nullptr, bb1);
  // w2: split-K=2 partials (f32) -> rA[0], rA[1]
  gemm128<5, 128, 2><<<32 * 8 * 2, 256, 0, stream>>>(tbuf, w2T, 4096, 1024, 4096, nullptr, rA, nullptr, nullptr);
  // ln2 fuses partial-sum + bias + residual
  ln_kernel<1><<<4096, 256, 0, stream>>>(rA, rA + (size_t)4096 * 1024, hbuf, bb2, g2, b2, (float*)d_out, nullptr);
}

// Round 6
// 267.114 us; speedup vs baseline: 1.7705x; 1.0348x over previous
//
#include <hip/hip_runtime.h>
#include <math.h>

typedef unsigned short u16;
typedef unsigned int u32;
typedef __bf16 bf16x8 __attribute__((ext_vector_type(8)));
typedef unsigned short us8 __attribute__((ext_vector_type(8)));
typedef unsigned short us4 __attribute__((ext_vector_type(4)));
typedef float f32x4 __attribute__((ext_vector_type(4)));

#define DEV __device__ __forceinline__

DEV float fast_exp2(float x) { return __builtin_amdgcn_exp2f(x); }

DEV u16 f2bf(float f) {
  __bf16 h = (__bf16)f;
  return __builtin_bit_cast(u16, h);
}
DEV float bf2f(u16 h) { return __builtin_bit_cast(float, (u32)h << 16); }

DEV bf16x8 ld_bf8(const u16* p) { return __builtin_bit_cast(bf16x8, *(const us8*)p); }

DEV void gload_lds16(const u16* g, u16* l) {
  __builtin_amdgcn_global_load_lds((const __attribute__((address_space(1))) void*)g,
                                   (__attribute__((address_space(3))) void*)l, 16, 0, 0);
}

DEV f32x4 mfma16(bf16x8 a, bf16x8 b, f32x4 c) {
  return __builtin_amdgcn_mfma_f32_16x16x32_bf16(a, b, c, 0, 0, 0);
}

#define BAR __builtin_amdgcn_s_barrier()
#define LGK asm volatile("s_waitcnt lgkmcnt(0)" ::: "memory")
#define VM4 asm volatile("s_waitcnt vmcnt(4)" ::: "memory")

// ---------------- prep kernels ----------------

__global__ void conv_bf16_kernel(const float* __restrict__ in, u16* __restrict__ out, int n4) {
  const int stride = gridDim.x * blockDim.x;
  for (int i = blockIdx.x * blockDim.x + threadIdx.x; i < n4; i += stride) {
    float4 v = ((const float4*)in)[i];
    us4 h; h[0] = f2bf(v.x); h[1] = f2bf(v.y); h[2] = f2bf(v.z); h[3] = f2bf(v.w);
    ((us4*)out)[i] = h;
  }
}

// in: K x N f32 (row-major) -> out: N x K bf16 (B^T), times scale.
// P=0 plain; P=1 permute OUT row c' = ((c&15)<<6)|(c>>4); P=2 gather IN row src=((r&63)<<4)|(r>>6)
template <int P>
__global__ __launch_bounds__(256) void transpose_bf16_kernel(
    const float* __restrict__ in, u16* __restrict__ out, int K, int N, float scale) {
  __shared__ float tile[32][33];
  const int nbk = K >> 5;
  const int bk = blockIdx.x % nbk, bn = blockIdx.x / nbk;
  const int r0 = bk << 5, c0 = bn << 5;
  const int t = threadIdx.x;
  {
    const int r = t >> 3, c4 = (t & 7) << 2;
    int sr = r0 + r;
    if constexpr (P == 2) sr = ((sr & 63) << 4) | (sr >> 6);
    const float4 v = *(const float4*)(in + (size_t)sr * N + c0 + c4);
    tile[r][c4] = v.x; tile[r][c4 + 1] = v.y; tile[r][c4 + 2] = v.z; tile[r][c4 + 3] = v.w;
  }
  __syncthreads();
  {
    const int oc = t >> 3, r4 = (t & 7) << 2;
    int orow = c0 + oc;
    if constexpr (P == 1) orow = ((orow & 15) << 6) | (orow >> 4);
    us4 h;
#pragma unroll
    for (int j = 0; j < 4; j++) h[j] = f2bf(tile[r4 + j][oc] * scale);
    *(us4*)(out + (size_t)orow * K + r0 + r4) = h;
  }
}

// k half of qk [b][l][1024 + n*64 + d] -> kth [b][n][d][l]
__global__ __launch_bounds__(256) void khead_transpose(
    const u16* __restrict__ qk, u16* __restrict__ kth) {
  __shared__ u16 tT[64 * 64];
  char* base = (char*)tT;
  const int t = threadIdx.x;
  const int bid = blockIdx.x;
  const int lt = bid & 31, n = (bid >> 5) & 15, b = bid >> 9;
#pragma unroll
  for (int rr = 0; rr < 2; rr++) {
    const int l = rr * 32 + (t >> 3);
    const int d0 = (t & 7) * 8;
    us8 v = *(const us8*)(qk + ((size_t)(b * 2048 + lt * 64 + l)) * 2048 + 1024 + n * 64 + d0);
#pragma unroll
    for (int j = 0; j < 8; j++) {
      const int d = d0 + j;
      *(u16*)(base + d * 128 + ((2 * l) ^ (16 * (d >> 3)))) = v[j];
    }
  }
  __syncthreads();
  const int w = t >> 6, lane = t & 63;
#pragma unroll
  for (int rr = 0; rr < 2; rr++) {
    const int d = rr * 32 + w * 8 + (lane >> 3);
    const int l = (lane & 7) * 8;
    us8 v = *(const us8*)(base + d * 128 + ((2 * l) ^ (16 * (d >> 3))));
    *(us8*)(kth + ((size_t)((b * 16 + n) * 64 + d)) * 2048 + lt * 64 + l) = v;
  }
}

// ---------------- 2-phase GEMM (qk / wo) ----------------
// MODE 0: ob = acc (bf16) ; MODE 2: of = acc + res (f32)
template <int MODE, int BN>
__global__ __launch_bounds__(256) void gemm128(
    const u16* __restrict__ A, const u16* __restrict__ BT,
    int M, int N, int K,
    u16* __restrict__ ob, float* __restrict__ of, const float* __restrict__ res) {
  constexpr int NJ = BN / 32;
  constexpr int WCC = BN / 2;
  __shared__ u16 As[2][4096];
  __shared__ u16 Bs[2][BN * 32];
  const int t = threadIdx.x;
  const int nbm = M >> 7;
  const int nblk = nbm * (N / BN);
  int bid = blockIdx.x;
  bid = (bid & 7) * (nblk >> 3) + (bid >> 3);
  const int bm = bid % nbm;
  const int bn = bid / nbm;
  const int m0 = bm << 7, n0 = bn * BN;
  const int w = t >> 6, lane = t & 63;
  const int wr = w >> 1, wc = w & 1;
  const int lr = lane & 15, lg = lane >> 4, lq = (lane >> 4) << 2;
  const int rsw = (lg ^ (lr & 3)) << 3;

  const int srow = t >> 2;
  const int sseg = (t & 3) ^ (srow & 3);
  const u16* ap = A + (size_t)(m0 + srow) * K + sseg * 8;
  const u16* bp = BT + (size_t)(n0 + srow) * K + sseg * 8;
  const size_t half = (size_t)64 * K;

#define STAGE(buf, k0)                                                 \
  {                                                                    \
    gload_lds16(ap + (k0), &As[buf][t << 3]);                          \
    gload_lds16(ap + half + (k0), &As[buf][(t << 3) + 2048]);          \
    gload_lds16(bp + (k0), &Bs[buf][t << 3]);                          \
    if constexpr (BN == 128)                                           \
      gload_lds16(bp + half + (k0), &Bs[buf][(t << 3) + 2048]);        \
  }

  f32x4 acc[4][NJ];
#pragma unroll
  for (int i = 0; i < 4; i++)
#pragma unroll
    for (int j = 0; j < NJ; j++) acc[i][j] = (f32x4){0.f, 0.f, 0.f, 0.f};

  STAGE(0, 0);
  __syncthreads();
  const int NI = K >> 5;
  for (int it = 0; it < NI; ++it) {
    const int buf = it & 1;
    if (it + 1 < NI) STAGE(buf ^ 1, (it + 1) << 5);
    bf16x8 af[4], bfr[NJ];
#pragma unroll
    for (int i = 0; i < 4; i++)
      af[i] = ld_bf8(&As[buf][(wr * 64 + i * 16 + lr) * 32 + rsw]);
#pragma unroll
    for (int j = 0; j < NJ; j++)
      bfr[j] = ld_bf8(&Bs[buf][(wc * WCC + j * 16 + lr) * 32 + rsw]);
#pragma unroll
    for (int i = 0; i < 4; i++)
#pragma unroll
      for (int j = 0; j < NJ; j++) acc[i][j] = mfma16(af[i], bfr[j], acc[i][j]);
    __syncthreads();
  }
#undef STAGE

#pragma unroll
  for (int i = 0; i < 4; i++) {
    const int r0 = m0 + wr * 64 + i * 16 + lq;
#pragma unroll
    for (int j = 0; j < NJ; j++) {
      const int c = n0 + wc * WCC + j * 16 + lr;
      if constexpr (MODE == 0) {
#pragma unroll
        for (int q = 0; q < 4; q++) ob[(size_t)(r0 + q) * N + c] = f2bf(acc[i][j][q]);
      } else {
#pragma unroll
        for (int q = 0; q < 4; q++) {
          const size_t idx = (size_t)(r0 + q) * N + c;
          of[idx] = acc[i][j][q] + res[idx];
        }
      }
    }
  }
}

// ---------------- 8-phase 256x256 GEMM (w1 / w2) ----------------
// BM=BN=256, BK=64, 512 thr (8 waves 2Mx4N), per-wave 128x64 out.
// LDS 128KB: AL/BL [buf][half][128x64], st_16x32 swizzle (seg ^= ((row>>2)&1)<<1)
// realized via pre-swizzled global_load_lds source + swizzled ds_read.
// 8 phases / 2 K-tiles; stage slot map (tile X read at P1-4 in buf0, X+1 at P5-8 in buf1):
//  P1: B1h0(X+1) P2: B1h1(X+1) P3: A0h0(X+2) P4: A0h1(X+2) [vmcnt(4)]
//  P5: B0h0(X+2) P6: B0h1(X+2) P7: A1h0(X+3) P8: A1h1(X+3) [vmcnt(4)]
// Tail tiles clamped (uniform vmcnt accounting, harmless refetch).
// MODE 0: ob = gelu(acc + bias) bf16 ; MODE 1: of[ks*M*N + .] = acc (f32 partial)
template <int MODE, int KS>
__global__ __launch_bounds__(512, 2) void gemm256(
    const u16* __restrict__ A, const u16* __restrict__ BT,
    int M, int N, int K,
    u16* __restrict__ ob, float* __restrict__ of, const float* __restrict__ bias) {
  __shared__ u16 AL[2][2][8192];
  __shared__ u16 BL[2][2][8192];
  const int t = threadIdx.x;
  const int lane = t & 63, wid = t >> 6;
  const int lr = lane & 15, lg = lane >> 4;
  const int wm = wid >> 2, wn = wid & 3;
  const int nbm = M >> 8, nbn = N >> 8;
  const int nblk = nbm * nbn * KS;
  int bid = blockIdx.x;
  bid = (bid & 7) * (nblk >> 3) + (bid >> 3);
  int ks = 0;
  if constexpr (KS > 1) { ks = bid % KS; bid /= KS; }
  const int bm = bid % nbm, bn = bid / nbm;
  const int m0 = bm << 8, n0 = bn << 8;
  const int KB = K / KS;
  const int NT = KB >> 6;
  const u16* Ag = A + (size_t)m0 * K + ks * KB;
  const u16* Bg = BT + (size_t)n0 * K + ks * KB;
  const int sseg = (t & 7) ^ (((t >> 5) & 1) << 1);
  const int akey = ((lr >> 2) & 1) << 1;

  auto stgA = [&](int buf, int h, int kt) {
    const u16* s = Ag + (size_t)(h * 128 + (t >> 3)) * K + kt * 64 + sseg * 8;
    gload_lds16(s, &AL[buf][h][t * 8]);
    gload_lds16(s + (size_t)64 * K, &AL[buf][h][4096 + t * 8]);
  };
  auto stgB = [&](int buf, int h, int kt) {
    const u16* s = Bg + (size_t)(h * 128 + (t >> 3)) * K + kt * 64 + sseg * 8;
    gload_lds16(s, &BL[buf][h][t * 8]);
    gload_lds16(s + (size_t)64 * K, &BL[buf][h][4096 + t * 8]);
  };

#define RDA(DST, BUF, IB)                                                      \
  _Pragma("unroll") for (int i4 = 0; i4 < 4; i4++)                             \
  _Pragma("unroll") for (int kk = 0; kk < 2; kk++)                             \
    DST[i4][kk] = ld_bf8(&AL[BUF][wm][((IB + i4) * 16 + lr) * 64 +             \
                                      ((kk * 4 + lg) ^ akey) * 8]);
#define RDB(DST, BUF, JB)                                                      \
  _Pragma("unroll") for (int j2 = 0; j2 < 2; j2++)                             \
  _Pragma("unroll") for (int kk = 0; kk < 2; kk++)                             \
    DST[j2][kk] = ld_bf8(&BL[BUF][wn >> 1][((wn & 1) * 64 + (JB + j2) * 16 +   \
                                            lr) * 64 +                         \
                                           ((kk * 4 + lg) ^ akey) * 8]);
#define QUAD(AF, BF, IB, JB)                                                   \
  __builtin_amdgcn_s_setprio(1);                                               \
  _Pragma("unroll") for (int i4 = 0; i4 < 4; i4++)                             \
  _Pragma("unroll") for (int j2 = 0; j2 < 2; j2++)                             \
  _Pragma("unroll") for (int kk = 0; kk < 2; kk++)                             \
    acc[IB + i4][JB + j2] = mfma16(AF[i4][kk], BF[j2][kk], acc[IB + i4][JB + j2]); \
  __builtin_amdgcn_s_setprio(0);

  f32x4 acc[8][4];
#pragma unroll
  for (int i = 0; i < 8; i++)
#pragma unroll
    for (int j = 0; j < 4; j++) acc[i][j] = (f32x4){0.f, 0.f, 0.f, 0.f};
  bf16x8 a0[4][2], a1[4][2], b0[2][2], b1[2][2];

  // prologue: tile0 fully, tile1 A-halves; retire tile0 (vmcnt(4) leaves tile1.A in flight)
  stgA(0, 0, 0); stgA(0, 1, 0); stgB(0, 0, 0); stgB(0, 1, 0);
  stgA(1, 0, 1); stgA(1, 1, 1);
  VM4;
  BAR;

  const int NI = NT >> 1;
  for (int it = 0; it < NI; ++it) {
    const int kt1 = 2 * it + 1;
    const int ktA = (2 * it + 2 < NT) ? 2 * it + 2 : NT - 1;
    const int ktB = (2 * it + 3 < NT) ? 2 * it + 3 : NT - 1;
    // P1
    RDA(a0, 0, 0); RDB(b0, 0, 0); stgB(1, 0, kt1);
    BAR; QUAD(a0, b0, 0, 0); LGK; BAR;
    // P2
    RDA(a1, 0, 4); stgB(1, 1, kt1);
    BAR; QUAD(a1, b0, 4, 0); LGK; BAR;
    // P3
    RDB(b1, 0, 2); stgA(0, 0, ktA);
    BAR; QUAD(a1, b1, 4, 2); LGK; BAR;
    // P4
    stgA(0, 1, ktA);
    BAR; QUAD(a0, b1, 0, 2); LGK; VM4; BAR;
    // P5
    RDA(a0, 1, 0); RDB(b0, 1, 0); stgB(0, 0, ktA);
    BAR; QUAD(a0, b0, 0, 0); LGK; BAR;
    // P6
    RDA(a1, 1, 4); stgB(0, 1, ktA);
    BAR; QUAD(a1, b0, 4, 0); LGK; BAR;
    // P7
    RDB(b1, 1, 2); stgA(1, 0, ktB);
    BAR; QUAD(a1, b1, 4, 2); LGK; BAR;
    // P8
    stgA(1, 1, ktB);
    BAR; QUAD(a0, b1, 0, 2); LGK; VM4; BAR;
  }
#undef RDA
#undef RDB
#undef QUAD

#pragma unroll
  for (int i = 0; i < 8; i++) {
    const int r = m0 + wm * 128 + i * 16 + lg * 4;
#pragma unroll
    for (int j = 0; j < 4; j++) {
      const int c = n0 + wn * 64 + j * 16 + lr;
      if constexpr (MODE == 0) {
        const float bv = bias[c];
#pragma unroll
        for (int q = 0; q < 4; q++) {
          float u = acc[i][j][q] + bv;
          ob[(size_t)(r + q) * N + c] = f2bf(0.5f * u * (1.f + erff(u * 0.70710678118f)));
        }
      } else {
        float* op = of + (size_t)ks * M * N;
#pragma unroll
        for (int q = 0; q < 4; q++) op[(size_t)(r + q) * N + c] = acc[i][j][q];
      }
    }
  }
}

// ---------------- attention ----------------
__global__ __launch_bounds__(256, 2) void attn_kernel(
    const u16* __restrict__ qk, const u16* __restrict__ kth, u16* __restrict__ ctxh) {
  __shared__ u16 KsB[2][4096];
  __shared__ u16 KtsB[2][4096];
  __shared__ u16 Plds[4][2048];
  const int t = threadIdx.x, w = t >> 6, lane = t & 63;
  const int lr = lane & 15, lg = lane >> 4;
  int bid = blockIdx.x;
  bid = (bid & 7) * 64 + (bid >> 3);
  const int qb = bid & 15, hn = (bid >> 4) & 15, b = bid >> 8;
  const int lw = qb * 128 + w * 32;
  const u16* ksrc = qk + (size_t)b * 2048 * 2048 + 1024 + hn * 64;
  const u16* ktb = kth + ((size_t)(b * 16 + hn)) * 64 * 2048;
  char* pb = (char*)&Plds[w][0];
  const int swz = (lr & 7) << 4;

#define STAGE_KV(buf, m0s)                                                    \
  {                                                                           \
    _Pragma("unroll") for (int i_ = 0; i_ < 2; i_++) {                        \
      const int s_ = t + 256 * i_;                                            \
      const int row_ = s_ >> 3;                                               \
      const int c_ = (s_ & 7) ^ (row_ & 7);                                   \
      gload_lds16(ksrc + (size_t)((m0s) + row_) * 2048 + c_ * 8,              \
                  &KsB[buf][s_ * 8]);                                         \
      gload_lds16(ktb + (size_t)row_ * 2048 + (m0s) + c_ * 8,                 \
                  &KtsB[buf][s_ * 8]);                                        \
    }                                                                         \
  }

  bf16x8 qf[2][2];
#pragma unroll
  for (int f = 0; f < 2; f++)
#pragma unroll
    for (int kk = 0; kk < 2; kk++)
      qf[f][kk] = ld_bf8(qk + (size_t)(b * 2048 + lw + 16 * f + lr) * 2048 + hn * 64 +
                         kk * 32 + lg * 8);

  float mrow[2] = {-1e30f, -1e30f}, lrow[2] = {0.f, 0.f};
  f32x4 o[2][4];
#pragma unroll
  for (int f = 0; f < 2; f++)
#pragma unroll
    for (int dj = 0; dj < 4; dj++) o[f][dj] = (f32x4){0.f, 0.f, 0.f, 0.f};

  STAGE_KV(0, 0);
  __syncthreads();

  for (int it = 0; it < 32; ++it) {
    const int buf = it & 1;
    if (it < 31) STAGE_KV(buf ^ 1, (it + 1) * 64);

    f32x4 sc[2][4];
#pragma unroll
    for (int f = 0; f < 2; f++)
#pragma unroll
      for (int mj = 0; mj < 4; mj++) sc[f][mj] = (f32x4){0.f, 0.f, 0.f, 0.f};
#pragma unroll
    for (int mj = 0; mj < 4; mj++) {
      const int krow = 16 * mj + lr;
      bf16x8 kf0 = ld_bf8(&KsB[buf][krow * 64 + ((lg ^ (krow & 7)) << 3)]);
      bf16x8 kf1 = ld_bf8(&KsB[buf][krow * 64 + (((4 + lg) ^ (krow & 7)) << 3)]);
#pragma unroll
      for (int f = 0; f < 2; f++) {
        sc[f][mj] = mfma16(kf0, qf[f][0], sc[f][mj]);
        sc[f][mj] = mfma16(kf1, qf[f][1], sc[f][mj]);
      }
    }

#pragma unroll
    for (int f = 0; f < 2; f++) {
      float tm = fmaxf(fmaxf(sc[f][0][0], sc[f][0][1]), fmaxf(sc[f][0][2], sc[f][0][3]));
#pragma unroll
      for (int mj = 1; mj < 4; mj++)
        tm = fmaxf(tm, fmaxf(fmaxf(sc[f][mj][0], sc[f][mj][1]),
                             fmaxf(sc[f][mj][2], sc[f][mj][3])));
      tm = fmaxf(tm, __shfl_xor(tm, 16));
      tm = fmaxf(tm, __shfl_xor(tm, 32));
      if (!__all(tm <= mrow[f] + 8.f)) {
        const float mnew = fmaxf(mrow[f], tm);
        const float al = fast_exp2(mrow[f] - mnew);
        mrow[f] = mnew;
        lrow[f] *= al;
        float albc[4];
#pragma unroll
        for (int q = 0; q < 4; q++) albc[q] = __shfl(al, 4 * lg + q);
#pragma unroll
        for (int dj = 0; dj < 4; dj++)
#pragma unroll
          for (int q = 0; q < 4; q++) o[f][dj][q] *= albc[q];
      }
      float ts = 0.f;
      char* pf = pb + f * 2048;
#pragma unroll
      for (int mj = 0; mj < 4; mj++) {
        float p0 = fast_exp2(sc[f][mj][0] - mrow[f]);
        float p1 = fast_exp2(sc[f][mj][1] - mrow[f]);
        float p2 = fast_exp2(sc[f][mj][2] - mrow[f]);
        float p3 = fast_exp2(sc[f][mj][3] - mrow[f]);
        ts += (p0 + p1) + (p2 + p3);
        u32 w0 = (u32)f2bf(p0) | ((u32)f2bf(p1) << 16);
        u32 w1 = (u32)f2bf(p2) | ((u32)f2bf(p3) << 16);
        *(uint2*)(pf + ((lr * 128 + mj * 32 + lg * 8) ^ swz)) = make_uint2(w0, w1);
      }
      ts += __shfl_xor(ts, 16);
      ts += __shfl_xor(ts, 32);
      lrow[f] += ts;
    }

    bf16x8 pa[2][2];
#pragma unroll
    for (int f = 0; f < 2; f++)
#pragma unroll
      for (int kk = 0; kk < 2; kk++)
        pa[f][kk] = __builtin_bit_cast(
            bf16x8, *(const us8*)(pb + f * 2048 + ((lr * 128 + kk * 64 + lg * 16) ^ swz)));

#pragma unroll
    for (int dj = 0; dj < 4; dj++) {
      const int vrow = dj * 16 + lr;
      bf16x8 v0 = ld_bf8(&KtsB[buf][vrow * 64 + ((lg ^ (vrow & 7)) << 3)]);
      bf16x8 v1 = ld_bf8(&KtsB[buf][vrow * 64 + (((4 + lg) ^ (vrow & 7)) << 3)]);
#pragma unroll
      for (int f = 0; f < 2; f++) {
        o[f][dj] = mfma16(pa[f][0], v0, o[f][dj]);
        o[f][dj] = mfma16(pa[f][1], v1, o[f][dj]);
      }
    }
    __syncthreads();
  }
#undef STAGE_KV

#pragma unroll
  for (int f = 0; f < 2; f++) {
    const float inv = 1.f / lrow[f];
    float invbc[4];
#pragma unroll
    for (int q = 0; q < 4; q++) invbc[q] = __shfl(inv, 4 * lg + q);
#pragma unroll
    for (int q = 0; q < 4; q++) {
      const int ll = lw + 16 * f + 4 * lg + q;
#pragma unroll
      for (int dj = 0; dj < 4; dj++) {
        ctxh[((size_t)(b * 2048 + ll)) * 1024 + hn * 64 + dj * 16 + lr] =
            f2bf(o[f][dj][q] * invbc[q]);
      }
    }
  }
}

// ---------------- layernorm ----------------
// ln1: in f32 -> LN -> bf16 out only
__global__ __launch_bounds__(256) void ln1_kernel(
    const float* __restrict__ in, const float* __restrict__ gamma,
    const float* __restrict__ beta, u16* __restrict__ o16) {
  __shared__ float red[8];
  const int row = blockIdx.x, t = threadIdx.x;
  const float4 v = ((const float4*)(in + (size_t)row * 1024))[t];
  float s = v.x + v.y + v.z + v.w;
  float ss = v.x * v.x + v.y * v.y + v.z * v.z + v.w * v.w;
#pragma unroll
  for (int off = 1; off < 64; off <<= 1) { s += __shfl_xor(s, off); ss += __shfl_xor(ss, off); }
  if ((t & 63) == 0) { red[t >> 6] = s; red[4 + (t >> 6)] = ss; }
  __syncthreads();
  const float st = red[0] + red[1] + red[2] + red[3];
  const float sst = red[4] + red[5] + red[6] + red[7];
  const float mean = st * (1.f / 1024.f);
  const float var = sst * (1.f / 1024.f) - mean * mean;
  const float rs = rsqrtf(var + 1e-5f);
  const float4 gv = ((const float4*)gamma)[t];
  const float4 bv = ((const float4*)beta)[t];
  us4 h;
  h[0] = f2bf((v.x - mean) * rs * gv.x + bv.x);
  h[1] = f2bf((v.y - mean) * rs * gv.y + bv.y);
  h[2] = f2bf((v.z - mean) * rs * gv.z + bv.z);
  h[3] = f2bf((v.w - mean) * rs * gv.w + bv.w);
  *(us4*)(o16 + (size_t)row * 1024 + t * 4) = h;
}

// ln2: NP f32 partials + bf16 residual + bias -> LN -> f32 out
template <int NP>
__global__ __launch_bounds__(256) void ln2_kernel(
    const float* __restrict__ p, size_t pstride,
    const u16* __restrict__ resb, const float* __restrict__ bias,
    const float* __restrict__ gamma, const float* __restrict__ beta,
    float* __restrict__ o32) {
  __shared__ float red[8];
  const int row = blockIdx.x, t = threadIdx.x;
  float4 v = ((const float4*)(p + (size_t)row * 1024))[t];
#pragma unroll
  for (int k = 1; k < NP; k++) {
    const float4 v2 = ((const float4*)(p + (size_t)k * pstride + (size_t)row * 1024))[t];
    v.x += v2.x; v.y += v2.y; v.z += v2.z; v.w += v2.w;
  }
  {
    const us4 rb = *(const us4*)(resb + (size_t)row * 1024 + t * 4);
    const float4 vb = ((const float4*)bias)[t];
    v.x += bf2f(rb[0]) + vb.x;
    v.y += bf2f(rb[1]) + vb.y;
    v.z += bf2f(rb[2]) + vb.z;
    v.w += bf2f(rb[3]) + vb.w;
  }
  float s = v.x + v.y + v.z + v.w;
  float ss = v.x * v.x + v.y * v.y + v.z * v.z + v.w * v.w;
#pragma unroll
  for (int off = 1; off < 64; off <<= 1) { s += __shfl_xor(s, off); ss += __shfl_xor(ss, off); }
  if ((t & 63) == 0) { red[t >> 6] = s; red[4 + (t >> 6)] = ss; }
  __syncthreads();
  const float st = red[0] + red[1] + red[2] + red[3];
  const float sst = red[4] + red[5] + red[6] + red[7];
  const float mean = st * (1.f / 1024.f);
  const float var = sst * (1.f / 1024.f) - mean * mean;
  const float rs = rsqrtf(var + 1e-5f);
  const float4 gv = ((const float4*)gamma)[t];
  const float4 bv = ((const float4*)beta)[t];
  float4 ov;
  ov.x = (v.x - mean) * rs * gv.x + bv.x;
  ov.y = (v.y - mean) * rs * gv.y + bv.y;
  ov.z = (v.z - mean) * rs * gv.z + bv.z;
  ov.w = (v.w - mean) * rs * gv.w + bv.w;
  ((float4*)(o32 + (size_t)row * 1024))[t] = ov;
}

// ---------------- launch ----------------
extern "C" void kernel_launch(void* const* d_in, const int* in_sizes, int n_in,
                              void* d_out, int out_size, void* d_ws, size_t ws_size,
                              hipStream_t stream) {
  const float* x   = (const float*)d_in[0];
  const float* wq  = (const float*)d_in[1];
  const float* wk  = (const float*)d_in[2];
  const float* wo  = (const float*)d_in[3];
  const float* g1  = (const float*)d_in[4];
  const float* b1  = (const float*)d_in[5];
  const float* w1  = (const float*)d_in[6];
  const float* bb1 = (const float*)d_in[7];
  const float* w2  = (const float*)d_in[8];
  const float* bb2 = (const float*)d_in[9];
  const float* g2  = (const float*)d_in[10];
  const float* b2  = (const float*)d_in[11];

  char* ws = (char*)d_ws;
  const size_t MB = 1ull << 20;
  // arena (peak 112 MB if KS=4 fits, else 96 MB with KS=2):
  u16* w2T   = (u16*)(ws + 0 * MB);     //  0-8   [prep -> w2]
  u16* hb    = (u16*)(ws + 8 * MB);     //  8-16  [ln1 -> w1, ln2 residual]
  u16* tbuf  = (u16*)(ws + 16 * MB);    // 16-48  [w1 -> w2] (overlays wqkT/xb/qk-head)
  float* rA  = (float*)(ws + 48 * MB);  // 48-112 [w2 partials -> ln2] (overlays the rest)
  u16* wqkT  = (u16*)(ws + 26 * MB);    // 26-30  [prep -> qkgemm]
  u16* xb    = (u16*)(ws + 30 * MB);    // 30-38  [conv -> qkgemm]
  u16* qk    = (u16*)(ws + 38 * MB);    // 38-54  [qkgemm -> attn]
  u16* kthp  = (u16*)(ws + 54 * MB);    // 54-62  [khead -> attn]
  u16* ctxh  = (u16*)(ws + 62 * MB);    // 62-70  [attn -> wo]
  float* rbuf = (float*)(ws + 70 * MB); // 70-86  [wo -> ln1]
  u16* w1T   = (u16*)(ws + 86 * MB);    // 86-94  [prep -> w1]
  u16* woT   = (u16*)(ws + 94 * MB);    // 94-96  [prep -> wo]

  const bool ks4 = ws_size >= 112 * MB;

  // prep
  conv_bf16_kernel<<<1024, 256, 0, stream>>>(x, xb, 1048576);
  transpose_bf16_kernel<1><<<1024, 256, 0, stream>>>(wq, wqkT, 1024, 1024, 0.125f * 1.44269504089f);
  transpose_bf16_kernel<1><<<1024, 256, 0, stream>>>(wk, wqkT + (size_t)1024 * 1024, 1024, 1024, 1.0f);
  transpose_bf16_kernel<2><<<1024, 256, 0, stream>>>(wo, woT, 1024, 1024, 1.0f);
  transpose_bf16_kernel<0><<<32 * 128, 256, 0, stream>>>(w1, w1T, 1024, 4096, 1.0f);
  transpose_bf16_kernel<0><<<128 * 32, 256, 0, stream>>>(w2, w2T, 4096, 1024, 1.0f);

  // q+k projection
  gemm128<0, 128><<<32 * 16, 256, 0, stream>>>(xb, wqkT, 4096, 2048, 1024, qk, nullptr, nullptr);
  khead_transpose<<<1024, 256, 0, stream>>>(qk, kthp);

  // attention (V := K per source bug)
  attn_kernel<<<512, 256, 0, stream>>>(qk, kthp, ctxh);

  // ctx @ wo + x -> rbuf ; LN1 -> hb (bf16)
  gemm128<2, 64><<<32 * 16, 256, 0, stream>>>(ctxh, woT, 4096, 1024, 1024, nullptr, rbuf, x);
  ln1_kernel<<<4096, 256, 0, stream>>>(rbuf, g1, b1, hb);

  // FFN: w1 (8-phase 256^2), w2 (8-phase 256^2 split-K), ln2 fuses reduce+bias+residual
  gemm256<0, 1><<<256, 512, 0, stream>>>(hb, w1T, 4096, 4096, 1024, tbuf, nullptr, bb1);
  const size_t MN = (size_t)4096 * 1024;
  if (ks4) {
    gemm256<1, 4><<<256, 512, 0, stream>>>(tbuf, w2T, 4096, 1024, 4096, nullptr, rA, nullptr);
    ln2_kernel<4><<<4096, 256, 0, stream>>>(rA, MN, hb, bb2, g2, b2, (float*)d_out);
  } else {
    gemm256<1, 2><<<128, 512, 0, stream>>>(tbuf, w2T, 4096, 1024, 4096, nullptr, rA, nullptr);
    ln2_kernel<2><<<4096, 256, 0, stream>>>(rA, MN, hb, bb2, g2, b2, (float*)d_out);
  }
}